// Round 1
// baseline (2299.149 us; speedup 1.0000x reference)
//
#include <hip/hip_runtime.h>
#include <hip/hip_bf16.h>
#include <math.h>

#define DIM 2048
#define NH 16
#define HD 128
#define BATCH 2
#define SEQ 2048
#define TOKENS (BATCH * SEQ)   // 4096

// ---------------------------------------------------------------------------
// GEMM: C[M,N] = (A[M,K] @ W[K,N] + bias[N]) * alpha      (all fp32, row-major)
// BM=BN=64, BK=16, 256 threads, 4x4 register tile per thread.
// ---------------------------------------------------------------------------
__global__ __launch_bounds__(256) void gemm_bias_f32(
    const float* __restrict__ A, const float* __restrict__ W,
    const float* __restrict__ bias, float* __restrict__ C,
    int M, int N, int K, float alpha)
{
    constexpr int BM = 64, BN = 64, BK = 16;
    __shared__ float As[BK][BM];   // transposed: As[k][m]
    __shared__ float Ws[BK][BN];   // Ws[k][n]

    const int tid = threadIdx.x;
    const int tx = tid % 16;       // n-dim
    const int ty = tid / 16;       // m-dim
    const int bm = blockIdx.y * BM;
    const int bn = blockIdx.x * BN;

    // global load assignments
    const int arow = tid / 4;            // 0..63
    const int acol = (tid % 4) * 4;      // 0,4,8,12
    const int wrow = tid / 16;           // 0..15
    const int wcol = (tid % 16) * 4;     // 0..60

    float acc[4][4] = {};

    for (int k0 = 0; k0 < K; k0 += BK) {
        const float4 av = *(const float4*)&A[(size_t)(bm + arow) * K + k0 + acol];
        const float4 wv = *(const float4*)&W[(size_t)(k0 + wrow) * N + bn + wcol];
        __syncthreads();   // previous-iter compute done before overwrite
        As[acol + 0][arow] = av.x;
        As[acol + 1][arow] = av.y;
        As[acol + 2][arow] = av.z;
        As[acol + 3][arow] = av.w;
        *(float4*)&Ws[wrow][wcol] = wv;
        __syncthreads();
#pragma unroll
        for (int kk = 0; kk < BK; ++kk) {
            const float4 a4 = *(const float4*)&As[kk][ty * 4];
            const float4 b4 = *(const float4*)&Ws[kk][tx * 4];
            const float ar[4] = {a4.x, a4.y, a4.z, a4.w};
            const float br[4] = {b4.x, b4.y, b4.z, b4.w};
#pragma unroll
            for (int i = 0; i < 4; ++i)
#pragma unroll
                for (int j = 0; j < 4; ++j)
                    acc[i][j] = fmaf(ar[i], br[j], acc[i][j]);
        }
    }

    const float4 bv = *(const float4*)&bias[bn + tx * 4];
    const float br[4] = {bv.x, bv.y, bv.z, bv.w};
#pragma unroll
    for (int i = 0; i < 4; ++i) {
        const size_t row = (size_t)(bm + ty * 4 + i);
        float4 outv;
        outv.x = (acc[i][0] + br[0]) * alpha;
        outv.y = (acc[i][1] + br[1]) * alpha;
        outv.z = (acc[i][2] + br[2]) * alpha;
        outv.w = (acc[i][3] + br[3]) * alpha;
        *(float4*)&C[row * N + bn + tx * 4] = outv;
    }
}

// ---------------------------------------------------------------------------
// Multi-query flash attention (fp32).
// Q: [TOKENS, DIM] laid out [b*SEQ+s][h*HD+d] (pre-scaled by 1/sqrt(HD))
// K,V: [TOKENS, HD];  O: [TOKENS, DIM] same layout as Q.
// Block: 256 threads, BQ=32 q-rows, BT=32 kv-rows per tile, full D=128.
// Thread (tr=tid/16, tc=tid%16): scores for rows {tr,tr+16} x cols {tc,tc+16};
// owns O rows {tr,tr+16} x d in {4tc..4tc+3, 64+4tc..64+4tc+3}.
// ---------------------------------------------------------------------------
__global__ __launch_bounds__(256) void mqa_attn_f32(
    const float* __restrict__ Q, const float* __restrict__ Kg,
    const float* __restrict__ Vg, float* __restrict__ O)
{
    constexpr int BQ = 32, BT = 32, QP = 132, PSP = 33;
    __shared__ float Qs[BQ][QP];
    __shared__ float Ks[BT][QP];
    __shared__ float Vs[BT][QP];
    __shared__ float Ps[BQ][PSP];

    const int tid = threadIdx.x;
    const int tc = tid % 16;
    const int tr = tid / 16;
    const int qt = blockIdx.x;
    const int h  = blockIdx.y;
    const int b  = blockIdx.z;

    const size_t qbase = (size_t)b * SEQ + (size_t)qt * BQ;   // token row
    const size_t kvbase = (size_t)b * SEQ;

    // stage Q tile: 32 rows x 128 floats = 1024 float4 / 256 threads
#pragma unroll
    for (int i = 0; i < 4; ++i) {
        const int idx = tid + i * 256;
        const int r = idx / 32;
        const int c4 = idx % 32;
        *(float4*)&Qs[r][c4 * 4] =
            *(const float4*)&Q[(qbase + r) * DIM + h * HD + c4 * 4];
    }

    float o[2][8] = {};
    float m0 = -INFINITY, m1 = -INFINITY, l0 = 0.f, l1 = 0.f;

    for (int t0 = 0; t0 < SEQ; t0 += BT) {
        __syncthreads();   // previous PV done; Q staged (first iter)
#pragma unroll
        for (int i = 0; i < 4; ++i) {
            const int idx = tid + i * 256;
            const int r = idx / 32;
            const int c4 = idx % 32;
            const size_t grow = kvbase + t0 + r;
            *(float4*)&Ks[r][c4 * 4] = *(const float4*)&Kg[grow * HD + c4 * 4];
            *(float4*)&Vs[r][c4 * 4] = *(const float4*)&Vg[grow * HD + c4 * 4];
        }
        __syncthreads();

        // ---- scores ----
        float s00 = 0.f, s01 = 0.f, s10 = 0.f, s11 = 0.f;
#pragma unroll
        for (int d = 0; d < HD; d += 4) {
            const float4 q0 = *(const float4*)&Qs[tr][d];
            const float4 q1 = *(const float4*)&Qs[tr + 16][d];
            const float4 k0 = *(const float4*)&Ks[tc][d];
            const float4 k1 = *(const float4*)&Ks[tc + 16][d];
            const float qa[4] = {q0.x, q0.y, q0.z, q0.w};
            const float qb[4] = {q1.x, q1.y, q1.z, q1.w};
            const float ka[4] = {k0.x, k0.y, k0.z, k0.w};
            const float kb[4] = {k1.x, k1.y, k1.z, k1.w};
#pragma unroll
            for (int j = 0; j < 4; ++j) {
                s00 = fmaf(qa[j], ka[j], s00);
                s01 = fmaf(qa[j], kb[j], s01);
                s10 = fmaf(qb[j], ka[j], s10);
                s11 = fmaf(qb[j], kb[j], s11);
            }
        }

        // ---- online softmax (row groups of 16 lanes) ----
        float pm0 = fmaxf(s00, s01);
        float pm1 = fmaxf(s10, s11);
#pragma unroll
        for (int msk = 1; msk < 16; msk <<= 1) {
            pm0 = fmaxf(pm0, __shfl_xor(pm0, msk, 64));
            pm1 = fmaxf(pm1, __shfl_xor(pm1, msk, 64));
        }
        const float mn0 = fmaxf(m0, pm0), mn1 = fmaxf(m1, pm1);
        const float a0 = __expf(m0 - mn0), a1 = __expf(m1 - mn1);
        const float p00 = __expf(s00 - mn0), p01 = __expf(s01 - mn0);
        const float p10 = __expf(s10 - mn1), p11 = __expf(s11 - mn1);
        float rs0 = p00 + p01, rs1 = p10 + p11;
#pragma unroll
        for (int msk = 1; msk < 16; msk <<= 1) {
            rs0 += __shfl_xor(rs0, msk, 64);
            rs1 += __shfl_xor(rs1, msk, 64);
        }
        l0 = l0 * a0 + rs0;
        l1 = l1 * a1 + rs1;
        m0 = mn0;
        m1 = mn1;

        Ps[tr][tc] = p00;
        Ps[tr][tc + 16] = p01;
        Ps[tr + 16][tc] = p10;
        Ps[tr + 16][tc + 16] = p11;

#pragma unroll
        for (int j = 0; j < 8; ++j) { o[0][j] *= a0; o[1][j] *= a1; }
        __syncthreads();   // Ps visible

        // ---- PV ----
#pragma unroll 4
        for (int c = 0; c < BT; ++c) {
            const float p0 = Ps[tr][c];
            const float p1 = Ps[tr + 16][c];
            const float4 va = *(const float4*)&Vs[c][tc * 4];
            const float4 vb = *(const float4*)&Vs[c][64 + tc * 4];
            const float vv[8] = {va.x, va.y, va.z, va.w, vb.x, vb.y, vb.z, vb.w};
#pragma unroll
            for (int j = 0; j < 8; ++j) {
                o[0][j] = fmaf(p0, vv[j], o[0][j]);
                o[1][j] = fmaf(p1, vv[j], o[1][j]);
            }
        }
    }

    // ---- epilogue ----
    const float inv0 = 1.f / l0, inv1 = 1.f / l1;
    const size_t row0 = qbase + tr, row1 = qbase + tr + 16;
    float4 w0a = {o[0][0] * inv0, o[0][1] * inv0, o[0][2] * inv0, o[0][3] * inv0};
    float4 w0b = {o[0][4] * inv0, o[0][5] * inv0, o[0][6] * inv0, o[0][7] * inv0};
    float4 w1a = {o[1][0] * inv1, o[1][1] * inv1, o[1][2] * inv1, o[1][3] * inv1};
    float4 w1b = {o[1][4] * inv1, o[1][5] * inv1, o[1][6] * inv1, o[1][7] * inv1};
    *(float4*)&O[row0 * DIM + h * HD + tc * 4] = w0a;
    *(float4*)&O[row0 * DIM + h * HD + 64 + tc * 4] = w0b;
    *(float4*)&O[row1 * DIM + h * HD + tc * 4] = w1a;
    *(float4*)&O[row1 * DIM + h * HD + 64 + tc * 4] = w1b;
}

// ---------------------------------------------------------------------------
extern "C" void kernel_launch(void* const* d_in, const int* in_sizes, int n_in,
                              void* d_out, int out_size, void* d_ws, size_t ws_size,
                              hipStream_t stream) {
    const float* x  = (const float*)d_in[0];
    const float* wq = (const float*)d_in[1];
    const float* bq = (const float*)d_in[2];
    const float* wk = (const float*)d_in[3];
    const float* bk = (const float*)d_in[4];
    const float* wv = (const float*)d_in[5];
    const float* bv = (const float*)d_in[6];
    const float* wo = (const float*)d_in[7];
    const float* bo = (const float*)d_in[8];
    float* out = (float*)d_out;

    float* qb = (float*)d_ws;
    float* kb = qb + (size_t)TOKENS * DIM;
    float* vb = kb + (size_t)TOKENS * HD;
    float* ob = vb + (size_t)TOKENS * HD;

    const float scale = 0.08838834764831845f;  // 1/sqrt(128)

    const dim3 blk(256);
    // Q = (x@wq + bq) * scale   (folding softmax scale into q)
    gemm_bias_f32<<<dim3(DIM / 64, TOKENS / 64), blk, 0, stream>>>(
        x, wq, bq, qb, TOKENS, DIM, DIM, scale);
    // K = x@wk + bk ; V = x@wv + bv
    gemm_bias_f32<<<dim3(HD / 64, TOKENS / 64), blk, 0, stream>>>(
        x, wk, bk, kb, TOKENS, HD, DIM, 1.0f);
    gemm_bias_f32<<<dim3(HD / 64, TOKENS / 64), blk, 0, stream>>>(
        x, wv, bv, vb, TOKENS, HD, DIM, 1.0f);
    // attention
    mqa_attn_f32<<<dim3(SEQ / 32, NH, BATCH), blk, 0, stream>>>(qb, kb, vb, ob);
    // out = o @ wo + bo
    gemm_bias_f32<<<dim3(DIM / 64, TOKENS / 64), blk, 0, stream>>>(
        ob, wo, bo, out, TOKENS, DIM, DIM, 1.0f);
}

// Round 2
// 1324.268 us; speedup vs baseline: 1.7362x; 1.7362x over previous
//
#include <hip/hip_runtime.h>
#include <hip/hip_bf16.h>
#include <math.h>

#define DIM 2048
#define NH 16
#define HD 128
#define BATCH 2
#define SEQ 2048
#define TOKENS (BATCH * SEQ)   // 4096

typedef __attribute__((ext_vector_type(8))) short bf16x8;
typedef __attribute__((ext_vector_type(4))) float f32x4;

__device__ __forceinline__ unsigned short f2bf(float f) {
    union { float f; unsigned int u; } v; v.f = f;
    unsigned int r = (v.u + 0x7FFFu + ((v.u >> 16) & 1u)) >> 16;
    return (unsigned short)r;
}

// ---------------------------------------------------------------------------
// GEMM: C = (A[M,K] @ W[K,N] + bias[N]) * alpha   (fp32).
// TRANS_OUT: write C^T [N,M] instead (used for V so attention reads V k-major).
// ---------------------------------------------------------------------------
template <bool TRANS_OUT>
__global__ __launch_bounds__(256) void gemm_bias_f32(
    const float* __restrict__ A, const float* __restrict__ W,
    const float* __restrict__ bias, float* __restrict__ C,
    int M, int N, int K, float alpha)
{
    constexpr int BM = 64, BN = 64, BK = 16;
    __shared__ float As[BK][BM];
    __shared__ float Ws[BK][BN];

    const int tid = threadIdx.x;
    const int tx = tid % 16;
    const int ty = tid / 16;
    const int bm = blockIdx.y * BM;
    const int bn = blockIdx.x * BN;

    const int arow = tid / 4;
    const int acol = (tid % 4) * 4;
    const int wrow = tid / 16;
    const int wcol = (tid % 16) * 4;

    float acc[4][4] = {};

    for (int k0 = 0; k0 < K; k0 += BK) {
        const float4 av = *(const float4*)&A[(size_t)(bm + arow) * K + k0 + acol];
        const float4 wv = *(const float4*)&W[(size_t)(k0 + wrow) * N + bn + wcol];
        __syncthreads();
        As[acol + 0][arow] = av.x;
        As[acol + 1][arow] = av.y;
        As[acol + 2][arow] = av.z;
        As[acol + 3][arow] = av.w;
        *(float4*)&Ws[wrow][wcol] = wv;
        __syncthreads();
#pragma unroll
        for (int kk = 0; kk < BK; ++kk) {
            const float4 a4 = *(const float4*)&As[kk][ty * 4];
            const float4 b4 = *(const float4*)&Ws[kk][tx * 4];
            const float ar[4] = {a4.x, a4.y, a4.z, a4.w};
            const float br[4] = {b4.x, b4.y, b4.z, b4.w};
#pragma unroll
            for (int i = 0; i < 4; ++i)
#pragma unroll
                for (int j = 0; j < 4; ++j)
                    acc[i][j] = fmaf(ar[i], br[j], acc[i][j]);
        }
    }

    const float4 bv = *(const float4*)&bias[bn + tx * 4];
    const float br[4] = {bv.x, bv.y, bv.z, bv.w};
    if (!TRANS_OUT) {
#pragma unroll
        for (int i = 0; i < 4; ++i) {
            const size_t row = (size_t)(bm + ty * 4 + i);
            float4 outv;
            outv.x = (acc[i][0] + br[0]) * alpha;
            outv.y = (acc[i][1] + br[1]) * alpha;
            outv.z = (acc[i][2] + br[2]) * alpha;
            outv.w = (acc[i][3] + br[3]) * alpha;
            *(float4*)&C[row * N + bn + tx * 4] = outv;
        }
    } else {
#pragma unroll
        for (int j = 0; j < 4; ++j) {
            const size_t row = (size_t)(bn + tx * 4 + j);   // N index
            float4 outv;
            outv.x = (acc[0][j] + br[j]) * alpha;
            outv.y = (acc[1][j] + br[j]) * alpha;
            outv.z = (acc[2][j] + br[j]) * alpha;
            outv.w = (acc[3][j] + br[j]) * alpha;
            *(float4*)&C[row * M + bm + ty * 4] = outv;     // C^T[N][M]
        }
    }
}

// ---------------------------------------------------------------------------
// MQA flash attention, bf16 MFMA (16x16x32).
// Q: [TOKENS, DIM] fp32 (pre-scaled); Kg: [TOKENS, HD] fp32;
// Vtg: V^T [HD, TOKENS] fp32; O: [TOKENS, DIM] fp32.
// Block = 256 thr = 4 waves; BQ=64 (16 q-rows/wave), BT=64, D=128.
// Wave w owns q-rows qt*64 + w*16 .. +15.
// Lane l: lr=l&15, lhi=l>>4.
//   score C-tile: S[q = 4*lhi + r][t = 16*ct + lr], r=0..3, ct=0..3
//   O accum:      O[q = 4*lhi + r][d = 16*dt + lr], dt=0..7
// ---------------------------------------------------------------------------
__global__ __launch_bounds__(256) void mqa_attn_bf16(
    const float* __restrict__ Q, const float* __restrict__ Kg,
    const float* __restrict__ Vtg, float* __restrict__ O)
{
    __shared__ __align__(16) unsigned short Ks[64][136];   // 17.0 KB (17-word rows)
    __shared__ __align__(16) unsigned short Vt[128][72];   // 18.0 KB (d-major)
    __shared__ __align__(16) unsigned short Ps[4][16][72]; //  9.0 KB (per wave)

    const int tid = threadIdx.x;
    const int wid = tid >> 6;
    const int lane = tid & 63;
    const int lr = lane & 15;
    const int lhi = lane >> 4;

    const int qt = blockIdx.x;
    const int h  = blockIdx.y;
    const int b  = blockIdx.z;
    const size_t bseq = (size_t)b * SEQ;
    const int q0 = qt * 64 + wid * 16;

    // ---- Q fragments in registers: qf[kk] covers k = kk*32 + lhi*8 .. +7 ----
    bf16x8 qf[4];
    {
        const float* qrow = Q + (bseq + q0 + lr) * DIM + (size_t)h * HD;
#pragma unroll
        for (int kk = 0; kk < 4; ++kk) {
            const float4 a = *(const float4*)(qrow + kk * 32 + lhi * 8);
            const float4 c = *(const float4*)(qrow + kk * 32 + lhi * 8 + 4);
            bf16x8 f;
            f[0] = f2bf(a.x); f[1] = f2bf(a.y); f[2] = f2bf(a.z); f[3] = f2bf(a.w);
            f[4] = f2bf(c.x); f[5] = f2bf(c.y); f[6] = f2bf(c.z); f[7] = f2bf(c.w);
            qf[kk] = f;
        }
    }

    f32x4 o[8];
#pragma unroll
    for (int dt = 0; dt < 8; ++dt) o[dt] = (f32x4){0.f, 0.f, 0.f, 0.f};
    float m[4] = {-INFINITY, -INFINITY, -INFINITY, -INFINITY};
    float lsum[4] = {0.f, 0.f, 0.f, 0.f};

    for (int t0 = 0; t0 < SEQ; t0 += 64) {
        __syncthreads();   // all waves done reading previous K/V tile
        // ---- stage K tile (row-major bf16) ----
#pragma unroll
        for (int i = 0; i < 8; ++i) {
            const int idx = tid + i * 256;      // 0..2047
            const int row = idx >> 5;           // 0..63
            const int c4 = idx & 31;            // float4 idx
            const float4 kv = *(const float4*)&Kg[(bseq + t0 + row) * HD + c4 * 4];
            ushort4 w;
            w.x = f2bf(kv.x); w.y = f2bf(kv.y); w.z = f2bf(kv.z); w.w = f2bf(kv.w);
            *(ushort4*)&Ks[row][c4 * 4] = w;
        }
        // ---- stage V^T tile (d-major bf16) ----
#pragma unroll
        for (int i = 0; i < 8; ++i) {
            const int idx = tid + i * 256;      // 0..2047
            const int d = idx >> 4;             // 0..127
            const int t4 = idx & 15;            // 0..15
            const float4 vv = *(const float4*)&Vtg[(size_t)d * TOKENS + bseq + t0 + t4 * 4];
            ushort4 w;
            w.x = f2bf(vv.x); w.y = f2bf(vv.y); w.z = f2bf(vv.z); w.w = f2bf(vv.w);
            *(ushort4*)&Vt[d][t4 * 4] = w;
        }
        __syncthreads();

        // ---- QK^T: S[16q][64t] per wave ----
        f32x4 sc[4];
#pragma unroll
        for (int ct = 0; ct < 4; ++ct) sc[ct] = (f32x4){0.f, 0.f, 0.f, 0.f};
#pragma unroll
        for (int kk = 0; kk < 4; ++kk) {
#pragma unroll
            for (int ct = 0; ct < 4; ++ct) {
                const bf16x8 kf = *(const bf16x8*)&Ks[ct * 16 + lr][kk * 32 + lhi * 8];
                sc[ct] = __builtin_amdgcn_mfma_f32_16x16x32_bf16(qf[kk], kf, sc[ct], 0, 0, 0);
            }
        }

        // ---- online softmax (rows live on 16-lane groups sharing lhi) ----
        float pm[4];
#pragma unroll
        for (int r = 0; r < 4; ++r)
            pm[r] = fmaxf(fmaxf(sc[0][r], sc[1][r]), fmaxf(sc[2][r], sc[3][r]));
#pragma unroll
        for (int msk = 1; msk < 16; msk <<= 1)
#pragma unroll
            for (int r = 0; r < 4; ++r)
                pm[r] = fmaxf(pm[r], __shfl_xor(pm[r], msk, 64));

        float al[4];
#pragma unroll
        for (int r = 0; r < 4; ++r) {
            const float mn = fmaxf(m[r], pm[r]);
            al[r] = __expf(m[r] - mn);
            m[r] = mn;
        }
        f32x4 p[4];
#pragma unroll
        for (int ct = 0; ct < 4; ++ct)
#pragma unroll
            for (int r = 0; r < 4; ++r)
                p[ct][r] = __expf(sc[ct][r] - m[r]);

        float rs[4];
#pragma unroll
        for (int r = 0; r < 4; ++r)
            rs[r] = (p[0][r] + p[1][r]) + (p[2][r] + p[3][r]);
#pragma unroll
        for (int msk = 1; msk < 16; msk <<= 1)
#pragma unroll
            for (int r = 0; r < 4; ++r)
                rs[r] += __shfl_xor(rs[r], msk, 64);
#pragma unroll
        for (int r = 0; r < 4; ++r)
            lsum[r] = lsum[r] * al[r] + rs[r];

        // ---- P (bf16) to per-wave LDS for A-fragment reshape ----
#pragma unroll
        for (int ct = 0; ct < 4; ++ct)
#pragma unroll
            for (int r = 0; r < 4; ++r)
                Ps[wid][lhi * 4 + r][ct * 16 + lr] = f2bf(p[ct][r]);

        // ---- rescale O ----
#pragma unroll
        for (int dt = 0; dt < 8; ++dt)
#pragma unroll
            for (int r = 0; r < 4; ++r)
                o[dt][r] *= al[r];

        // ---- PV: O[16q][128d] += P[16q][64t] @ V[64t][128d] ----
#pragma unroll
        for (int kk = 0; kk < 2; ++kk) {
            const bf16x8 pa = *(const bf16x8*)&Ps[wid][lr][kk * 32 + lhi * 8];
#pragma unroll
            for (int dt = 0; dt < 8; ++dt) {
                const bf16x8 vb = *(const bf16x8*)&Vt[dt * 16 + lr][kk * 32 + lhi * 8];
                o[dt] = __builtin_amdgcn_mfma_f32_16x16x32_bf16(pa, vb, o[dt], 0, 0, 0);
            }
        }
    }

    // ---- epilogue: normalize and store ----
    float inv[4];
#pragma unroll
    for (int r = 0; r < 4; ++r) inv[r] = 1.f / lsum[r];
#pragma unroll
    for (int r = 0; r < 4; ++r) {
        float* op = O + (bseq + q0 + lhi * 4 + r) * DIM + (size_t)h * HD + lr;
#pragma unroll
        for (int dt = 0; dt < 8; ++dt)
            op[dt * 16] = o[dt][r] * inv[r];
    }
}

// ---------------------------------------------------------------------------
extern "C" void kernel_launch(void* const* d_in, const int* in_sizes, int n_in,
                              void* d_out, int out_size, void* d_ws, size_t ws_size,
                              hipStream_t stream) {
    const float* x  = (const float*)d_in[0];
    const float* wq = (const float*)d_in[1];
    const float* bq = (const float*)d_in[2];
    const float* wk = (const float*)d_in[3];
    const float* bk = (const float*)d_in[4];
    const float* wv = (const float*)d_in[5];
    const float* bv = (const float*)d_in[6];
    const float* wo = (const float*)d_in[7];
    const float* bo = (const float*)d_in[8];
    float* out = (float*)d_out;

    float* qb  = (float*)d_ws;                       // [TOKENS, DIM]
    float* kb  = qb  + (size_t)TOKENS * DIM;         // [TOKENS, HD]
    float* vtb = kb  + (size_t)TOKENS * HD;          // V^T [HD, TOKENS]
    float* ob  = vtb + (size_t)TOKENS * HD;          // [TOKENS, DIM]

    const float scale = 0.08838834764831845f;  // 1/sqrt(128)
    const dim3 blk(256);

    gemm_bias_f32<false><<<dim3(DIM / 64, TOKENS / 64), blk, 0, stream>>>(
        x, wq, bq, qb, TOKENS, DIM, DIM, scale);
    gemm_bias_f32<false><<<dim3(HD / 64, TOKENS / 64), blk, 0, stream>>>(
        x, wk, bk, kb, TOKENS, HD, DIM, 1.0f);
    gemm_bias_f32<true><<<dim3(HD / 64, TOKENS / 64), blk, 0, stream>>>(
        x, wv, bv, vtb, TOKENS, HD, DIM, 1.0f);

    mqa_attn_bf16<<<dim3(SEQ / 64, NH, BATCH), blk, 0, stream>>>(qb, kb, vtb, ob);

    gemm_bias_f32<false><<<dim3(DIM / 64, TOKENS / 64), blk, 0, stream>>>(
        ob, wo, bo, out, TOKENS, DIM, DIM, 1.0f);
}

// Round 3
// 585.784 us; speedup vs baseline: 3.9249x; 2.2607x over previous
//
#include <hip/hip_runtime.h>
#include <hip/hip_bf16.h>
#include <math.h>

#define DIM 2048
#define NH 16
#define HD 128
#define BATCH 2
#define SEQ 2048
#define TOKENS (BATCH * SEQ)   // 4096
#define NQKV (DIM + 2 * HD)    // 2304

typedef __attribute__((ext_vector_type(8))) short bf16x8;
typedef __attribute__((ext_vector_type(8))) unsigned short ushort8v;
typedef __attribute__((ext_vector_type(4))) float f32x4;
typedef unsigned short u16;

__device__ __forceinline__ u16 f2bf(float f) {
    union { float f; unsigned int u; } v; v.f = f;
    unsigned int r = (v.u + 0x7FFFu + ((v.u >> 16) & 1u)) >> 16;
    return (u16)r;
}
__device__ __forceinline__ float bf2f(u16 h) {
    union { unsigned int u; float f; } v; v.u = ((unsigned int)h) << 16;
    return v.f;
}
__device__ __forceinline__ void gll16(const void* g, void* l) {
    __builtin_amdgcn_global_load_lds(
        (const __attribute__((address_space(1))) unsigned int*)g,
        (__attribute__((address_space(3))) unsigned int*)l, 16, 0, 0);
}

// ---------------------------------------------------------------------------
// prep: elementwise split fp32 -> (hi, lo) bf16.  n4 = count/4 (exact).
// ---------------------------------------------------------------------------
__global__ __launch_bounds__(256) void split_bf16(
    const float* __restrict__ in, u16* __restrict__ hi, u16* __restrict__ lo)
{
    const int i = blockIdx.x * 256 + threadIdx.x;
    const float4 v = ((const float4*)in)[i];
    ushort4 h, l;
    h.x = f2bf(v.x); l.x = f2bf(v.x - bf2f(h.x));
    h.y = f2bf(v.y); l.y = f2bf(v.y - bf2f(h.y));
    h.z = f2bf(v.z); l.z = f2bf(v.z - bf2f(h.z));
    h.w = f2bf(v.w); l.w = f2bf(v.w - bf2f(h.w));
    ((ushort4*)hi)[i] = h;
    ((ushort4*)lo)[i] = l;
}

// ---------------------------------------------------------------------------
// prep: W [K][N] fp32 -> W^T hi/lo bf16 [N][K] at row offset rowoff.
// ---------------------------------------------------------------------------
__global__ __launch_bounds__(256) void transpose_split(
    const float* __restrict__ W, u16* __restrict__ Th, u16* __restrict__ Tl,
    int K, int N, int rowoff)
{
    __shared__ float tile[32][33];
    const int k0 = blockIdx.x * 32;
    const int n0 = blockIdx.y * 32;
    const int tid = threadIdx.x;
#pragma unroll
    for (int i = 0; i < 4; ++i) {
        const int idx = tid + i * 256;
        const int r = idx >> 5, c = idx & 31;
        tile[r][c] = W[(size_t)(k0 + r) * N + n0 + c];
    }
    __syncthreads();
#pragma unroll
    for (int i = 0; i < 4; ++i) {
        const int idx = tid + i * 256;
        const int r = idx >> 5, c = idx & 31;     // r = n-local, c = k-local
        const float v = tile[c][r];
        const u16 hv = f2bf(v);
        const size_t off = (size_t)(rowoff + n0 + r) * K + k0 + c;
        Th[off] = hv;
        Tl[off] = f2bf(v - bf2f(hv));
    }
}

__global__ __launch_bounds__(256) void concat_bias(
    const float* __restrict__ bq, const float* __restrict__ bk,
    const float* __restrict__ bv, float* __restrict__ bc)
{
    const int i = blockIdx.x * 256 + threadIdx.x;   // 0..2303
    float v;
    if (i < DIM) v = bq[i];
    else if (i < DIM + HD) v = bk[i - DIM];
    else v = bv[i - DIM - HD];
    bc[i] = v;
}

// ---------------------------------------------------------------------------
// Split-bf16 GEMM: C = (Ahi+Alo)[M,2048] @ (Bhi+Blo)^T + bias, 3-MFMA-pass.
// A: [M][2048] bf16 hi/lo.  B: [Nrows][2048] bf16 hi/lo (row n = col n of W).
// 128x128 tile, BK=32, 256 thr = 4 waves (2x2 of 64x64).
// MODE 0: QKV multi-dest epilogue (q bf16 scaled | k bf16 | v^T bf16).
// MODE 1: fp32 out [M][DIM] (O-projection), alpha=1.
// ---------------------------------------------------------------------------
template <int MODE>
__global__ __launch_bounds__(256) void gemm_split(
    const u16* __restrict__ Ah, const u16* __restrict__ Al,
    const u16* __restrict__ Bh, const u16* __restrict__ Bl,
    const float* __restrict__ bias, float* __restrict__ Cf,
    u16* __restrict__ qdst, u16* __restrict__ kdst, u16* __restrict__ vtdst,
    float scale)
{
    constexpr int BK = 32;
    __shared__ u16 lds[4 * 128 * BK];   // Ah | Al | Bh | Bl : 8 KB each

    const int tid = threadIdx.x;
    const int wid = tid >> 6;
    const int lane = tid & 63;
    const int lr = lane & 15;
    const int lhi = lane >> 4;
    const int wr = wid >> 1, wc = wid & 1;
    const int bm = blockIdx.y * 128;
    const int bn = blockIdx.x * 128;

    f32x4 acc[4][4];
#pragma unroll
    for (int i = 0; i < 4; ++i)
#pragma unroll
        for (int j = 0; j < 4; ++j) acc[i][j] = (f32x4){0.f, 0.f, 0.f, 0.f};

    for (int k0 = 0; k0 < DIM; k0 += BK) {
        __syncthreads();   // all waves done reading previous tile
#pragma unroll
        for (int rr = 0; rr < 2; ++rr) {
            const int slot = rr * 256 + tid;
            const int row = slot >> 2;
            const int ch = (slot & 3) * 8;
            char* lbase = (char*)lds + (size_t)(rr * 256 + wid * 64) * 16;
            const size_t ga = (size_t)(bm + row) * DIM + k0 + ch;
            const size_t gb = (size_t)(bn + row) * DIM + k0 + ch;
            gll16(Ah + ga, lbase);
            gll16(Al + ga, lbase + 8192);
            gll16(Bh + gb, lbase + 16384);
            gll16(Bl + gb, lbase + 24576);
        }
        __syncthreads();   // vmcnt drained -> staged data visible

        bf16x8 ah[4], al[4], bh[4], bl[4];
#pragma unroll
        for (int i = 0; i < 4; ++i) {
            const int mrow = wr * 64 + i * 16 + lr;
            const int nrow = wc * 64 + i * 16 + lr;
            ah[i] = *(const bf16x8*)&lds[mrow * BK + lhi * 8];
            al[i] = *(const bf16x8*)&lds[4096 + mrow * BK + lhi * 8];
            bh[i] = *(const bf16x8*)&lds[8192 + nrow * BK + lhi * 8];
            bl[i] = *(const bf16x8*)&lds[12288 + nrow * BK + lhi * 8];
        }
#pragma unroll
        for (int i = 0; i < 4; ++i)
#pragma unroll
            for (int j = 0; j < 4; ++j) {
                acc[i][j] = __builtin_amdgcn_mfma_f32_16x16x32_bf16(ah[i], bh[j], acc[i][j], 0, 0, 0);
                acc[i][j] = __builtin_amdgcn_mfma_f32_16x16x32_bf16(ah[i], bl[j], acc[i][j], 0, 0, 0);
                acc[i][j] = __builtin_amdgcn_mfma_f32_16x16x32_bf16(al[i], bh[j], acc[i][j], 0, 0, 0);
            }
    }

    // ---- epilogue ----
    const float alpha = (MODE == 0 && bn < DIM) ? scale : 1.0f;
    float bj[4];
#pragma unroll
    for (int j = 0; j < 4; ++j) bj[j] = bias[bn + wc * 64 + j * 16 + lr];

#pragma unroll
    for (int i = 0; i < 4; ++i) {
#pragma unroll
        for (int j = 0; j < 4; ++j) {
#pragma unroll
            for (int r = 0; r < 4; ++r) {
                const int row = bm + wr * 64 + i * 16 + lhi * 4 + r;
                const int col = bn + wc * 64 + j * 16 + lr;
                const float val = (acc[i][j][r] + bj[j]) * alpha;
                if (MODE == 1) {
                    Cf[(size_t)row * DIM + col] = val;
                } else if (bn < DIM) {
                    qdst[(size_t)row * DIM + col] = f2bf(val);
                } else if (bn < DIM + HD) {
                    kdst[(size_t)row * HD + (col - DIM)] = f2bf(val);
                } else {
                    vtdst[(size_t)(col - DIM - HD) * TOKENS + row] = f2bf(val);
                }
            }
        }
    }
}

// ---------------------------------------------------------------------------
// MQA flash attention, bf16 in / split-bf16 out.
// Q: [TOKENS, DIM] bf16 (pre-scaled); Kg: [TOKENS, HD] bf16;
// Vtg: V^T [HD, TOKENS] bf16; Ohi/Olo: [TOKENS, DIM] bf16.
// ---------------------------------------------------------------------------
__global__ __launch_bounds__(256) void mqa_attn_bf16(
    const u16* __restrict__ Q, const u16* __restrict__ Kg,
    const u16* __restrict__ Vtg, u16* __restrict__ Ohi, u16* __restrict__ Olo)
{
    __shared__ __align__(16) u16 Ks[64][136];
    __shared__ __align__(16) u16 Vt[128][72];
    __shared__ __align__(16) u16 Ps[4][16][72];

    const int tid = threadIdx.x;
    const int wid = tid >> 6;
    const int lane = tid & 63;
    const int lr = lane & 15;
    const int lhi = lane >> 4;

    const int qt = blockIdx.x;
    const int h  = blockIdx.y;
    const int b  = blockIdx.z;
    const size_t bseq = (size_t)b * SEQ;
    const int q0 = qt * 64 + wid * 16;

    // Q fragments straight from bf16 global
    bf16x8 qf[4];
    {
        const u16* qrow = Q + (bseq + q0 + lr) * DIM + (size_t)h * HD;
#pragma unroll
        for (int kk = 0; kk < 4; ++kk)
            qf[kk] = *(const bf16x8*)(qrow + kk * 32 + lhi * 8);
    }

    f32x4 o[8];
#pragma unroll
    for (int dt = 0; dt < 8; ++dt) o[dt] = (f32x4){0.f, 0.f, 0.f, 0.f};
    float m[4] = {-INFINITY, -INFINITY, -INFINITY, -INFINITY};
    float lsum[4] = {0.f, 0.f, 0.f, 0.f};

    for (int t0 = 0; t0 < SEQ; t0 += 64) {
        __syncthreads();
        // stage K tile: 64x128 bf16 -> 1024 chunks of 8
#pragma unroll
        for (int i = 0; i < 4; ++i) {
            const int idx = tid + i * 256;
            const int row = idx >> 4;
            const int c8 = (idx & 15) * 8;
            *(ushort8v*)&Ks[row][c8] =
                *(const ushort8v*)&Kg[(bseq + t0 + row) * HD + c8];
        }
        // stage V^T tile: 128 d-rows x 64 t
#pragma unroll
        for (int i = 0; i < 4; ++i) {
            const int idx = tid + i * 256;
            const int d = idx >> 3;
            const int t8 = (idx & 7) * 8;
            *(ushort8v*)&Vt[d][t8] =
                *(const ushort8v*)&Vtg[(size_t)d * TOKENS + bseq + t0 + t8];
        }
        __syncthreads();

        // QK^T
        f32x4 sc[4];
#pragma unroll
        for (int ct = 0; ct < 4; ++ct) sc[ct] = (f32x4){0.f, 0.f, 0.f, 0.f};
#pragma unroll
        for (int kk = 0; kk < 4; ++kk)
#pragma unroll
            for (int ct = 0; ct < 4; ++ct) {
                const bf16x8 kf = *(const bf16x8*)&Ks[ct * 16 + lr][kk * 32 + lhi * 8];
                sc[ct] = __builtin_amdgcn_mfma_f32_16x16x32_bf16(qf[kk], kf, sc[ct], 0, 0, 0);
            }

        // online softmax
        float pm[4];
#pragma unroll
        for (int r = 0; r < 4; ++r)
            pm[r] = fmaxf(fmaxf(sc[0][r], sc[1][r]), fmaxf(sc[2][r], sc[3][r]));
#pragma unroll
        for (int msk = 1; msk < 16; msk <<= 1)
#pragma unroll
            for (int r = 0; r < 4; ++r)
                pm[r] = fmaxf(pm[r], __shfl_xor(pm[r], msk, 64));

        float al[4];
#pragma unroll
        for (int r = 0; r < 4; ++r) {
            const float mn = fmaxf(m[r], pm[r]);
            al[r] = __expf(m[r] - mn);
            m[r] = mn;
        }
        f32x4 p[4];
#pragma unroll
        for (int ct = 0; ct < 4; ++ct)
#pragma unroll
            for (int r = 0; r < 4; ++r)
                p[ct][r] = __expf(sc[ct][r] - m[r]);

        float rs[4];
#pragma unroll
        for (int r = 0; r < 4; ++r)
            rs[r] = (p[0][r] + p[1][r]) + (p[2][r] + p[3][r]);
#pragma unroll
        for (int msk = 1; msk < 16; msk <<= 1)
#pragma unroll
            for (int r = 0; r < 4; ++r)
                rs[r] += __shfl_xor(rs[r], msk, 64);
#pragma unroll
        for (int r = 0; r < 4; ++r)
            lsum[r] = lsum[r] * al[r] + rs[r];

#pragma unroll
        for (int ct = 0; ct < 4; ++ct)
#pragma unroll
            for (int r = 0; r < 4; ++r)
                Ps[wid][lhi * 4 + r][ct * 16 + lr] = f2bf(p[ct][r]);

#pragma unroll
        for (int dt = 0; dt < 8; ++dt)
#pragma unroll
            for (int r = 0; r < 4; ++r)
                o[dt][r] *= al[r];

        // PV
#pragma unroll
        for (int kk = 0; kk < 2; ++kk) {
            const bf16x8 pa = *(const bf16x8*)&Ps[wid][lr][kk * 32 + lhi * 8];
#pragma unroll
            for (int dt = 0; dt < 8; ++dt) {
                const bf16x8 vb = *(const bf16x8*)&Vt[dt * 16 + lr][kk * 32 + lhi * 8];
                o[dt] = __builtin_amdgcn_mfma_f32_16x16x32_bf16(pa, vb, o[dt], 0, 0, 0);
            }
        }
    }

    // epilogue: normalize, split-write bf16 hi/lo
#pragma unroll
    for (int r = 0; r < 4; ++r) {
        const float inv = 1.f / lsum[r];
        const size_t base = (bseq + q0 + lhi * 4 + r) * DIM + (size_t)h * HD + lr;
        u16* oph = Ohi + base;
        u16* opl = Olo + base;
#pragma unroll
        for (int dt = 0; dt < 8; ++dt) {
            const float val = o[dt][r] * inv;
            const u16 hv = f2bf(val);
            oph[dt * 16] = hv;
            opl[dt * 16] = f2bf(val - bf2f(hv));
        }
    }
}

// ---------------------------------------------------------------------------
extern "C" void kernel_launch(void* const* d_in, const int* in_sizes, int n_in,
                              void* d_out, int out_size, void* d_ws, size_t ws_size,
                              hipStream_t stream) {
    const float* x  = (const float*)d_in[0];
    const float* wq = (const float*)d_in[1];
    const float* bq = (const float*)d_in[2];
    const float* wk = (const float*)d_in[3];
    const float* bk = (const float*)d_in[4];
    const float* wv = (const float*)d_in[5];
    const float* bv = (const float*)d_in[6];
    const float* wo = (const float*)d_in[7];
    const float* bo = (const float*)d_in[8];
    float* out = (float*)d_out;

    char* w = (char*)d_ws;
    u16* x_hi   = (u16*)w;                 w += (size_t)TOKENS * DIM * 2;   // 16 MB
    u16* x_lo   = (u16*)w;                 w += (size_t)TOKENS * DIM * 2;
    u16* wcat_h = (u16*)w;                 w += (size_t)NQKV * DIM * 2;     // 9 MB
    u16* wcat_l = (u16*)w;                 w += (size_t)NQKV * DIM * 2;
    u16* wo_h   = (u16*)w;                 w += (size_t)DIM * DIM * 2;      // 8 MB
    u16* wo_l   = (u16*)w;                 w += (size_t)DIM * DIM * 2;
    u16* qb     = (u16*)w;                 w += (size_t)TOKENS * DIM * 2;   // 16 MB
    u16* kb     = (u16*)w;                 w += (size_t)TOKENS * HD * 2;    // 1 MB
    u16* vtb    = (u16*)w;                 w += (size_t)TOKENS * HD * 2;
    float* bc   = (float*)w;               w += 16384;
    u16* Ohi = x_hi;   // x dead after QKV GEMM; stream order makes this safe
    u16* Olo = x_lo;

    const float scale = 0.08838834764831845f;  // 1/sqrt(128)
    const dim3 blk(256);

    // prep
    split_bf16<<<TOKENS * DIM / 4 / 256, blk, 0, stream>>>(x, x_hi, x_lo);
    transpose_split<<<dim3(DIM / 32, DIM / 32), blk, 0, stream>>>(wq, wcat_h, wcat_l, DIM, DIM, 0);
    transpose_split<<<dim3(DIM / 32, HD / 32), blk, 0, stream>>>(wk, wcat_h, wcat_l, DIM, HD, DIM);
    transpose_split<<<dim3(DIM / 32, HD / 32), blk, 0, stream>>>(wv, wcat_h, wcat_l, DIM, HD, DIM + HD);
    transpose_split<<<dim3(DIM / 32, DIM / 32), blk, 0, stream>>>(wo, wo_h, wo_l, DIM, DIM, 0);
    concat_bias<<<NQKV / 256, blk, 0, stream>>>(bq, bk, bv, bc);

    // fused QKV projection (split-3 MFMA)
    gemm_split<0><<<dim3(NQKV / 128, TOKENS / 128), blk, 0, stream>>>(
        x_hi, x_lo, wcat_h, wcat_l, bc, nullptr, qb, kb, vtb, scale);

    // attention
    mqa_attn_bf16<<<dim3(SEQ / 64, NH, BATCH), blk, 0, stream>>>(qb, kb, vtb, Ohi, Olo);

    // output projection (split-3 MFMA, fp32 out)
    gemm_split<1><<<dim3(DIM / 128, TOKENS / 128), blk, 0, stream>>>(
        Ohi, Olo, wo_h, wo_l, bo, out, nullptr, nullptr, nullptr, 1.0f);
}

// Round 4
// 445.069 us; speedup vs baseline: 5.1658x; 1.3162x over previous
//
#include <hip/hip_runtime.h>
#include <hip/hip_bf16.h>
#include <math.h>

#define DIM 2048
#define NH 16
#define HD 128
#define BATCH 2
#define SEQ 2048
#define TOKENS (BATCH * SEQ)   // 4096
#define NQKV (DIM + 2 * HD)    // 2304

typedef __attribute__((ext_vector_type(8))) short bf16x8;
typedef __attribute__((ext_vector_type(8))) unsigned short ushort8v;
typedef __attribute__((ext_vector_type(4))) float f32x4;
typedef unsigned short u16;

__device__ __forceinline__ u16 f2bf(float f) {
    union { float f; unsigned int u; } v; v.f = f;
    unsigned int r = (v.u + 0x7FFFu + ((v.u >> 16) & 1u)) >> 16;
    return (u16)r;
}
__device__ __forceinline__ float bf2f(u16 h) {
    union { unsigned int u; float f; } v; v.u = ((unsigned int)h) << 16;
    return v.f;
}
__device__ __forceinline__ void gll16(const void* g, void* l) {
    __builtin_amdgcn_global_load_lds(
        (const __attribute__((address_space(1))) unsigned int*)g,
        (__attribute__((address_space(3))) unsigned int*)l, 16, 0, 0);
}

// XOR-swizzled LDS index helpers (u16 element index; col*2 must keep 16B
// alignment for b128 accesses — all fragment columns are multiples of 8 u16).
#define KIDX(r, c) ((r) * 128 + (((((c) << 1)) ^ (((r) & 7) << 4)) >> 1))
#define VIDX(d, c) ((d) * 64  + (((((c) << 1)) ^ (((d) & 7) << 4)) >> 1))
#define PIDX(r, c) ((r) * 64  + (((((c) << 1)) ^ (((r) & 7) << 4)) >> 1))

// ---------------------------------------------------------------------------
// prep kernels
// ---------------------------------------------------------------------------
__global__ __launch_bounds__(256) void split_bf16(
    const float* __restrict__ in, u16* __restrict__ hi, u16* __restrict__ lo)
{
    const int i = blockIdx.x * 256 + threadIdx.x;
    const float4 v = ((const float4*)in)[i];
    ushort4 h, l;
    h.x = f2bf(v.x); l.x = f2bf(v.x - bf2f(h.x));
    h.y = f2bf(v.y); l.y = f2bf(v.y - bf2f(h.y));
    h.z = f2bf(v.z); l.z = f2bf(v.z - bf2f(h.z));
    h.w = f2bf(v.w); l.w = f2bf(v.w - bf2f(h.w));
    ((ushort4*)hi)[i] = h;
    ((ushort4*)lo)[i] = l;
}

__global__ __launch_bounds__(256) void transpose_split(
    const float* __restrict__ W, u16* __restrict__ Th, u16* __restrict__ Tl,
    int K, int N, int rowoff)
{
    __shared__ float tile[32][33];
    const int k0 = blockIdx.x * 32;
    const int n0 = blockIdx.y * 32;
    const int tid = threadIdx.x;
#pragma unroll
    for (int i = 0; i < 4; ++i) {
        const int idx = tid + i * 256;
        const int r = idx >> 5, c = idx & 31;
        tile[r][c] = W[(size_t)(k0 + r) * N + n0 + c];
    }
    __syncthreads();
#pragma unroll
    for (int i = 0; i < 4; ++i) {
        const int idx = tid + i * 256;
        const int r = idx >> 5, c = idx & 31;
        const float v = tile[c][r];
        const u16 hv = f2bf(v);
        const size_t off = (size_t)(rowoff + n0 + r) * K + k0 + c;
        Th[off] = hv;
        Tl[off] = f2bf(v - bf2f(hv));
    }
}

__global__ __launch_bounds__(256) void concat_bias(
    const float* __restrict__ bq, const float* __restrict__ bk,
    const float* __restrict__ bv, float* __restrict__ bc)
{
    const int i = blockIdx.x * 256 + threadIdx.x;
    float v;
    if (i < DIM) v = bq[i];
    else if (i < DIM + HD) v = bk[i - DIM];
    else v = bv[i - DIM - HD];
    bc[i] = v;
}

// ---------------------------------------------------------------------------
// Split-bf16 GEMM (3-pass hi/lo), 128x128 tile, BK=32, global_load_lds.
// ---------------------------------------------------------------------------
template <int MODE>
__global__ __launch_bounds__(256) void gemm_split(
    const u16* __restrict__ Ah, const u16* __restrict__ Al,
    const u16* __restrict__ Bh, const u16* __restrict__ Bl,
    const float* __restrict__ bias, float* __restrict__ Cf,
    u16* __restrict__ qdst, u16* __restrict__ kdst, u16* __restrict__ vtdst,
    float scale)
{
    constexpr int BK = 32;
    __shared__ u16 lds[4 * 128 * BK];

    const int tid = threadIdx.x;
    const int wid = tid >> 6;
    const int lane = tid & 63;
    const int lr = lane & 15;
    const int lhi = lane >> 4;
    const int wr = wid >> 1, wc = wid & 1;
    const int bm = blockIdx.y * 128;
    const int bn = blockIdx.x * 128;

    f32x4 acc[4][4];
#pragma unroll
    for (int i = 0; i < 4; ++i)
#pragma unroll
        for (int j = 0; j < 4; ++j) acc[i][j] = (f32x4){0.f, 0.f, 0.f, 0.f};

    for (int k0 = 0; k0 < DIM; k0 += BK) {
        __syncthreads();
#pragma unroll
        for (int rr = 0; rr < 2; ++rr) {
            const int slot = rr * 256 + tid;
            const int row = slot >> 2;
            const int ch = (slot & 3) * 8;
            char* lbase = (char*)lds + (size_t)(rr * 256 + wid * 64) * 16;
            const size_t ga = (size_t)(bm + row) * DIM + k0 + ch;
            const size_t gb = (size_t)(bn + row) * DIM + k0 + ch;
            gll16(Ah + ga, lbase);
            gll16(Al + ga, lbase + 8192);
            gll16(Bh + gb, lbase + 16384);
            gll16(Bl + gb, lbase + 24576);
        }
        __syncthreads();

        bf16x8 ah[4], al[4], bh[4], bl[4];
#pragma unroll
        for (int i = 0; i < 4; ++i) {
            const int mrow = wr * 64 + i * 16 + lr;
            const int nrow = wc * 64 + i * 16 + lr;
            ah[i] = *(const bf16x8*)&lds[mrow * BK + lhi * 8];
            al[i] = *(const bf16x8*)&lds[4096 + mrow * BK + lhi * 8];
            bh[i] = *(const bf16x8*)&lds[8192 + nrow * BK + lhi * 8];
            bl[i] = *(const bf16x8*)&lds[12288 + nrow * BK + lhi * 8];
        }
#pragma unroll
        for (int i = 0; i < 4; ++i)
#pragma unroll
            for (int j = 0; j < 4; ++j) {
                acc[i][j] = __builtin_amdgcn_mfma_f32_16x16x32_bf16(ah[i], bh[j], acc[i][j], 0, 0, 0);
                acc[i][j] = __builtin_amdgcn_mfma_f32_16x16x32_bf16(ah[i], bl[j], acc[i][j], 0, 0, 0);
                acc[i][j] = __builtin_amdgcn_mfma_f32_16x16x32_bf16(al[i], bh[j], acc[i][j], 0, 0, 0);
            }
    }

    const float alpha = (MODE == 0 && bn < DIM) ? scale : 1.0f;
    float bj[4];
#pragma unroll
    for (int j = 0; j < 4; ++j) bj[j] = bias[bn + wc * 64 + j * 16 + lr];

#pragma unroll
    for (int i = 0; i < 4; ++i) {
#pragma unroll
        for (int j = 0; j < 4; ++j) {
#pragma unroll
            for (int r = 0; r < 4; ++r) {
                const int row = bm + wr * 64 + i * 16 + lhi * 4 + r;
                const int col = bn + wc * 64 + j * 16 + lr;
                const float val = (acc[i][j][r] + bj[j]) * alpha;
                if (MODE == 1) {
                    Cf[(size_t)row * DIM + col] = val;
                } else if (bn < DIM) {
                    qdst[(size_t)row * DIM + col] = f2bf(val);
                } else if (bn < DIM + HD) {
                    kdst[(size_t)row * HD + (col - DIM)] = f2bf(val);
                } else {
                    vtdst[(size_t)(col - DIM - HD) * TOKENS + row] = f2bf(val);
                }
            }
        }
    }
}

// ---------------------------------------------------------------------------
// MQA flash attention, bf16 MFMA, swizzled LDS + async-staged K/V.
// ---------------------------------------------------------------------------
__global__ __launch_bounds__(256) void mqa_attn_bf16(
    const u16* __restrict__ Q, const u16* __restrict__ Kg,
    const u16* __restrict__ Vtg, u16* __restrict__ Ohi, u16* __restrict__ Olo)
{
    __shared__ __align__(16) u16 Ks[64 * 128];    // 16 KB, XOR-swizzled
    __shared__ __align__(16) u16 Vt[128 * 64];    // 16 KB, XOR-swizzled
    __shared__ __align__(16) u16 Ps[4][16 * 64];  //  8 KB, per-wave, swizzled

    const int tid = threadIdx.x;
    const int wid = tid >> 6;
    const int lane = tid & 63;
    const int lr = lane & 15;
    const int lhi = lane >> 4;

    const int qt = blockIdx.x;
    const int h  = blockIdx.y;
    const int b  = blockIdx.z;
    const size_t bseq = (size_t)b * SEQ;
    const int q0 = qt * 64 + wid * 16;

    // Q fragments (bf16, pre-scaled by 1/sqrt(HD) in the QKV GEMM epilogue)
    bf16x8 qf[4];
    {
        const u16* qrow = Q + (bseq + q0 + lr) * DIM + (size_t)h * HD;
#pragma unroll
        for (int kk = 0; kk < 4; ++kk)
            qf[kk] = *(const bf16x8*)(qrow + kk * 32 + lhi * 8);
    }

    bf16x8 ones;
#pragma unroll
    for (int j = 0; j < 8; ++j) ones[j] = (short)0x3F80;   // bf16 1.0

    f32x4 o[8];
#pragma unroll
    for (int dt = 0; dt < 8; ++dt) o[dt] = (f32x4){0.f, 0.f, 0.f, 0.f};
    float m[4] = {-INFINITY, -INFINITY, -INFINITY, -INFINITY};
    float lsum[4] = {0.f, 0.f, 0.f, 0.f};

    // register staging for K/V tiles (issue-early / write-late, T14)
    ushort8v kreg[4], vreg[4];
#define LOAD_KV(t0_)                                                          \
    {                                                                         \
        _Pragma("unroll")                                                     \
        for (int i = 0; i < 4; ++i) {                                         \
            const int idx = tid + i * 256;                                    \
            kreg[i] = *(const ushort8v*)&Kg[(bseq + (t0_) + (idx >> 4)) * HD  \
                                            + (idx & 15) * 8];                \
            vreg[i] = *(const ushort8v*)&Vtg[(size_t)(idx >> 3) * TOKENS      \
                                             + bseq + (t0_) + (idx & 7) * 8]; \
        }                                                                     \
    }

    LOAD_KV(0);

    for (int t0 = 0; t0 < SEQ; t0 += 64) {
        __syncthreads();   // all waves done reading previous K/V tile
#pragma unroll
        for (int i = 0; i < 4; ++i) {
            const int idx = tid + i * 256;
            *(ushort8v*)&Ks[KIDX(idx >> 4, (idx & 15) * 8)] = kreg[i];
            *(ushort8v*)&Vt[VIDX(idx >> 3, (idx & 7) * 8)] = vreg[i];
        }
        __syncthreads();
        if (t0 + 64 < SEQ) LOAD_KV(t0 + 64);   // overlap with compute below

        // ---- QK^T ----
        f32x4 sc[4];
#pragma unroll
        for (int ct = 0; ct < 4; ++ct) sc[ct] = (f32x4){0.f, 0.f, 0.f, 0.f};
        __builtin_amdgcn_s_setprio(1);
#pragma unroll
        for (int kk = 0; kk < 4; ++kk)
#pragma unroll
            for (int ct = 0; ct < 4; ++ct) {
                const bf16x8 kf = *(const bf16x8*)&Ks[KIDX(ct * 16 + lr, kk * 32 + lhi * 8)];
                sc[ct] = __builtin_amdgcn_mfma_f32_16x16x32_bf16(qf[kk], kf, sc[ct], 0, 0, 0);
            }
        __builtin_amdgcn_s_setprio(0);

        // ---- row max (16-lane groups) ----
        float pm[4];
#pragma unroll
        for (int r = 0; r < 4; ++r)
            pm[r] = fmaxf(fmaxf(sc[0][r], sc[1][r]), fmaxf(sc[2][r], sc[3][r]));
#pragma unroll
        for (int msk = 1; msk < 16; msk <<= 1)
#pragma unroll
            for (int r = 0; r < 4; ++r)
                pm[r] = fmaxf(pm[r], __shfl_xor(pm[r], msk, 64));

        // ---- defer-max (T13, THR=8) ----
        float al[4];
        bool need = false;
#pragma unroll
        for (int r = 0; r < 4; ++r) {
            if (pm[r] > m[r] + 8.f) {
                al[r] = __expf(m[r] - pm[r]);
                m[r] = pm[r];
                need = true;
            } else {
                al[r] = 1.f;
            }
        }

        // ---- P = exp(S - m), bf16, to per-wave swizzled LDS ----
#pragma unroll
        for (int ct = 0; ct < 4; ++ct)
#pragma unroll
            for (int r = 0; r < 4; ++r)
                Ps[wid][PIDX(lhi * 4 + r, ct * 16 + lr)] = f2bf(__expf(sc[ct][r] - m[r]));

        if (need) {
#pragma unroll
            for (int dt = 0; dt < 8; ++dt)
#pragma unroll
                for (int r = 0; r < 4; ++r)
                    o[dt][r] *= al[r];
        }

        // ---- PV + l (l = P @ ones shares the accumulator layout) ----
        f32x4 lacc = (f32x4){0.f, 0.f, 0.f, 0.f};
        __builtin_amdgcn_s_setprio(1);
#pragma unroll
        for (int kk = 0; kk < 2; ++kk) {
            const bf16x8 pa = *(const bf16x8*)&Ps[wid][PIDX(lr, kk * 32 + lhi * 8)];
            lacc = __builtin_amdgcn_mfma_f32_16x16x32_bf16(pa, ones, lacc, 0, 0, 0);
#pragma unroll
            for (int dt = 0; dt < 8; ++dt) {
                const bf16x8 vb = *(const bf16x8*)&Vt[VIDX(dt * 16 + lr, kk * 32 + lhi * 8)];
                o[dt] = __builtin_amdgcn_mfma_f32_16x16x32_bf16(pa, vb, o[dt], 0, 0, 0);
            }
        }
        __builtin_amdgcn_s_setprio(0);
#pragma unroll
        for (int r = 0; r < 4; ++r)
            lsum[r] = lsum[r] * al[r] + lacc[r];
    }

    // ---- epilogue: normalize, split-write bf16 hi/lo ----
#pragma unroll
    for (int r = 0; r < 4; ++r) {
        const float inv = 1.f / lsum[r];
        const size_t base = (bseq + q0 + lhi * 4 + r) * DIM + (size_t)h * HD + lr;
        u16* oph = Ohi + base;
        u16* opl = Olo + base;
#pragma unroll
        for (int dt = 0; dt < 8; ++dt) {
            const float val = o[dt][r] * inv;
            const u16 hv = f2bf(val);
            oph[dt * 16] = hv;
            opl[dt * 16] = f2bf(val - bf2f(hv));
        }
    }
}

// ---------------------------------------------------------------------------
extern "C" void kernel_launch(void* const* d_in, const int* in_sizes, int n_in,
                              void* d_out, int out_size, void* d_ws, size_t ws_size,
                              hipStream_t stream) {
    const float* x  = (const float*)d_in[0];
    const float* wq = (const float*)d_in[1];
    const float* bq = (const float*)d_in[2];
    const float* wk = (const float*)d_in[3];
    const float* bk = (const float*)d_in[4];
    const float* wv = (const float*)d_in[5];
    const float* bv = (const float*)d_in[6];
    const float* wo = (const float*)d_in[7];
    const float* bo = (const float*)d_in[8];
    float* out = (float*)d_out;

    char* w = (char*)d_ws;
    u16* x_hi   = (u16*)w;                 w += (size_t)TOKENS * DIM * 2;
    u16* x_lo   = (u16*)w;                 w += (size_t)TOKENS * DIM * 2;
    u16* wcat_h = (u16*)w;                 w += (size_t)NQKV * DIM * 2;
    u16* wcat_l = (u16*)w;                 w += (size_t)NQKV * DIM * 2;
    u16* wo_h   = (u16*)w;                 w += (size_t)DIM * DIM * 2;
    u16* wo_l   = (u16*)w;                 w += (size_t)DIM * DIM * 2;
    u16* qb     = (u16*)w;                 w += (size_t)TOKENS * DIM * 2;
    u16* kb     = (u16*)w;                 w += (size_t)TOKENS * HD * 2;
    u16* vtb    = (u16*)w;                 w += (size_t)TOKENS * HD * 2;
    float* bc   = (float*)w;               w += 16384;
    u16* Ohi = x_hi;   // x dead after QKV GEMM; stream order makes this safe
    u16* Olo = x_lo;

    const float scale = 0.08838834764831845f;  // 1/sqrt(128)
    const dim3 blk(256);

    split_bf16<<<TOKENS * DIM / 4 / 256, blk, 0, stream>>>(x, x_hi, x_lo);
    transpose_split<<<dim3(DIM / 32, DIM / 32), blk, 0, stream>>>(wq, wcat_h, wcat_l, DIM, DIM, 0);
    transpose_split<<<dim3(DIM / 32, HD / 32), blk, 0, stream>>>(wk, wcat_h, wcat_l, DIM, HD, DIM);
    transpose_split<<<dim3(DIM / 32, HD / 32), blk, 0, stream>>>(wv, wcat_h, wcat_l, DIM, HD, DIM + HD);
    transpose_split<<<dim3(DIM / 32, DIM / 32), blk, 0, stream>>>(wo, wo_h, wo_l, DIM, DIM, 0);
    concat_bias<<<NQKV / 256, blk, 0, stream>>>(bq, bk, bv, bc);

    gemm_split<0><<<dim3(NQKV / 128, TOKENS / 128), blk, 0, stream>>>(
        x_hi, x_lo, wcat_h, wcat_l, bc, nullptr, qb, kb, vtb, scale);

    mqa_attn_bf16<<<dim3(SEQ / 64, NH, BATCH), blk, 0, stream>>>(qb, kb, vtb, Ohi, Olo);

    gemm_split<1><<<dim3(DIM / 128, TOKENS / 128), blk, 0, stream>>>(
        Ohi, Olo, wo_h, wo_l, bo, out, nullptr, nullptr, nullptr, 1.0f);
}

// Round 5
// 406.683 us; speedup vs baseline: 5.6534x; 1.0944x over previous
//
#include <hip/hip_runtime.h>
#include <hip/hip_bf16.h>
#include <math.h>

#define DIM 2048
#define NH 16
#define HD 128
#define BATCH 2
#define SEQ 2048
#define TOKENS (BATCH * SEQ)   // 4096
#define NQKV (DIM + 2 * HD)    // 2304

typedef __attribute__((ext_vector_type(8))) short bf16x8;
typedef __attribute__((ext_vector_type(8))) unsigned short ushort8v;
typedef __attribute__((ext_vector_type(4))) float f32x4;
typedef unsigned short u16;

__device__ __forceinline__ u16 f2bf(float f) {
    union { float f; unsigned int u; } v; v.f = f;
    unsigned int r = (v.u + 0x7FFFu + ((v.u >> 16) & 1u)) >> 16;
    return (u16)r;
}
__device__ __forceinline__ float bf2f(u16 h) {
    union { unsigned int u; float f; } v; v.u = ((unsigned int)h) << 16;
    return v.f;
}
__device__ __forceinline__ void gll16(const void* g, void* l) {
    __builtin_amdgcn_global_load_lds(
        (const __attribute__((address_space(1))) unsigned int*)g,
        (__attribute__((address_space(3))) unsigned int*)l, 16, 0, 0);
}

// Attention LDS swizzles (write+read symmetric, reg-staged so both sides swizzle)
#define KIDX(r, c) ((r) * 128 + (((((c) << 1)) ^ (((r) & 7) << 4)) >> 1))
#define VIDX(d, c) ((d) * 64  + (((((c) << 1)) ^ (((d) & 7) << 4)) >> 1))
#define PIDX(r, c) ((r) * 64  + (((((c) << 1)) ^ (((r) & 7) << 4)) >> 1))

// ---------------------------------------------------------------------------
// prep kernels
// ---------------------------------------------------------------------------
__global__ __launch_bounds__(256) void split_bf16(
    const float* __restrict__ in, u16* __restrict__ hi, u16* __restrict__ lo)
{
    const int i = blockIdx.x * 256 + threadIdx.x;
    const float4 v = ((const float4*)in)[i];
    ushort4 h, l;
    h.x = f2bf(v.x); l.x = f2bf(v.x - bf2f(h.x));
    h.y = f2bf(v.y); l.y = f2bf(v.y - bf2f(h.y));
    h.z = f2bf(v.z); l.z = f2bf(v.z - bf2f(h.z));
    h.w = f2bf(v.w); l.w = f2bf(v.w - bf2f(h.w));
    ((ushort4*)hi)[i] = h;
    ((ushort4*)lo)[i] = l;
}

__global__ __launch_bounds__(256) void transpose_split(
    const float* __restrict__ W, u16* __restrict__ Th, u16* __restrict__ Tl,
    int K, int N, int rowoff)
{
    __shared__ float tile[32][33];
    const int k0 = blockIdx.x * 32;
    const int n0 = blockIdx.y * 32;
    const int tid = threadIdx.x;
#pragma unroll
    for (int i = 0; i < 4; ++i) {
        const int idx = tid + i * 256;
        const int r = idx >> 5, c = idx & 31;
        tile[r][c] = W[(size_t)(k0 + r) * N + n0 + c];
    }
    __syncthreads();
#pragma unroll
    for (int i = 0; i < 4; ++i) {
        const int idx = tid + i * 256;
        const int r = idx >> 5, c = idx & 31;
        const float v = tile[c][r];
        const u16 hv = f2bf(v);
        const size_t off = (size_t)(rowoff + n0 + r) * K + k0 + c;
        Th[off] = hv;
        Tl[off] = f2bf(v - bf2f(hv));
    }
}

__global__ __launch_bounds__(256) void concat_bias(
    const float* __restrict__ bq, const float* __restrict__ bk,
    const float* __restrict__ bv, float* __restrict__ bc)
{
    const int i = blockIdx.x * 256 + threadIdx.x;
    float v;
    if (i < DIM) v = bq[i];
    else if (i < DIM + HD) v = bk[i - DIM];
    else v = bv[i - DIM - HD];
    bc[i] = v;
}

// ---------------------------------------------------------------------------
// Split-bf16 GEMM (3-pass hi/lo), 128x128 tile, BK=32.
// Double-buffered LDS; next K-tile staged via global_load_lds BEFORE compute
// (one vmcnt-drain+barrier per K-step — T3 minimum 2-phase).
// Bank-conflict fix (rule #21): LDS dest linear, global source chunk
// pre-swizzled  chunk ^= (row>>1)&3 ; reads apply the same XOR.
//   read bank = 16*(row&1) + 4*(lhi ^ ((row>>1)&3)) -> 8 bank-quads,
//   2 lanes each = conflict-free.
// ---------------------------------------------------------------------------
template <int MODE>
__global__ __launch_bounds__(256) void gemm_split(
    const u16* __restrict__ Ah, const u16* __restrict__ Al,
    const u16* __restrict__ Bh, const u16* __restrict__ Bl,
    const float* __restrict__ bias, float* __restrict__ Cf,
    u16* __restrict__ qdst, u16* __restrict__ kdst, u16* __restrict__ vtdst,
    float scale)
{
    constexpr int BK = 32;
    __shared__ u16 lds[2][4 * 128 * BK];   // 2 x (Ah|Al|Bh|Bl @ 8KB) = 64 KB

    const int tid = threadIdx.x;
    const int wid = tid >> 6;
    const int lane = tid & 63;
    const int lr = lane & 15;
    const int lhi = lane >> 4;
    const int wr = wid >> 1, wc = wid & 1;
    const int bm = blockIdx.y * 128;
    const int bn = blockIdx.x * 128;

    f32x4 acc[4][4];
#pragma unroll
    for (int i = 0; i < 4; ++i)
#pragma unroll
        for (int j = 0; j < 4; ++j) acc[i][j] = (f32x4){0.f, 0.f, 0.f, 0.f};

    // stage K-tile k0_ into lds[buf_]; lane slot -> (row, lds-chunk), global
    // chunk = lds-chunk ^ ((row>>1)&3)  (involution; read side applies same)
#define STAGE(buf_, k0_)                                                      \
    {                                                                         \
        _Pragma("unroll")                                                     \
        for (int rr = 0; rr < 2; ++rr) {                                      \
            const int slot = rr * 256 + tid;                                  \
            const int row = slot >> 2;                                        \
            const int gch = ((slot & 3) ^ ((row >> 1) & 3)) * 8;              \
            char* lbase = (char*)lds[buf_] + (size_t)(rr * 256 + wid * 64) * 16; \
            const size_t ga = (size_t)(bm + row) * DIM + (k0_) + gch;         \
            const size_t gb = (size_t)(bn + row) * DIM + (k0_) + gch;         \
            gll16(Ah + ga, lbase);                                            \
            gll16(Al + ga, lbase + 8192);                                     \
            gll16(Bh + gb, lbase + 16384);                                    \
            gll16(Bl + gb, lbase + 24576);                                    \
        }                                                                     \
    }

    STAGE(0, 0);
    __syncthreads();   // drains vmcnt (compiler emits full waitcnt before barrier)

    int cur = 0;
    for (int k0 = 0; k0 < DIM; k0 += BK) {
        if (k0 + BK < DIM) STAGE(cur ^ 1, k0 + BK);   // loads fly under MFMA

        bf16x8 ah[4], al[4], bh[4], bl[4];
#pragma unroll
        for (int i = 0; i < 4; ++i) {
            const int mrow = wr * 64 + i * 16 + lr;
            const int nrow = wc * 64 + i * 16 + lr;
            const int mo = mrow * BK + ((lhi ^ ((mrow >> 1) & 3)) * 8);
            const int no = nrow * BK + ((lhi ^ ((nrow >> 1) & 3)) * 8);
            ah[i] = *(const bf16x8*)&lds[cur][mo];
            al[i] = *(const bf16x8*)&lds[cur][4096 + mo];
            bh[i] = *(const bf16x8*)&lds[cur][8192 + no];
            bl[i] = *(const bf16x8*)&lds[cur][12288 + no];
        }
        __builtin_amdgcn_s_setprio(1);
#pragma unroll
        for (int i = 0; i < 4; ++i)
#pragma unroll
            for (int j = 0; j < 4; ++j) {
                acc[i][j] = __builtin_amdgcn_mfma_f32_16x16x32_bf16(ah[i], bh[j], acc[i][j], 0, 0, 0);
                acc[i][j] = __builtin_amdgcn_mfma_f32_16x16x32_bf16(ah[i], bl[j], acc[i][j], 0, 0, 0);
                acc[i][j] = __builtin_amdgcn_mfma_f32_16x16x32_bf16(al[i], bh[j], acc[i][j], 0, 0, 0);
            }
        __builtin_amdgcn_s_setprio(0);
        __syncthreads();   // drain this iter's STAGE + release read buffer
        cur ^= 1;
    }
#undef STAGE

    const float alpha = (MODE == 0 && bn < DIM) ? scale : 1.0f;
    float bj[4];
#pragma unroll
    for (int j = 0; j < 4; ++j) bj[j] = bias[bn + wc * 64 + j * 16 + lr];

#pragma unroll
    for (int i = 0; i < 4; ++i) {
#pragma unroll
        for (int j = 0; j < 4; ++j) {
#pragma unroll
            for (int r = 0; r < 4; ++r) {
                const int row = bm + wr * 64 + i * 16 + lhi * 4 + r;
                const int col = bn + wc * 64 + j * 16 + lr;
                const float val = (acc[i][j][r] + bj[j]) * alpha;
                if (MODE == 1) {
                    Cf[(size_t)row * DIM + col] = val;
                } else if (bn < DIM) {
                    qdst[(size_t)row * DIM + col] = f2bf(val);
                } else if (bn < DIM + HD) {
                    kdst[(size_t)row * HD + (col - DIM)] = f2bf(val);
                } else {
                    vtdst[(size_t)(col - DIM - HD) * TOKENS + row] = f2bf(val);
                }
            }
        }
    }
}

// ---------------------------------------------------------------------------
// MQA flash attention, bf16 MFMA, swizzled LDS + async-staged K/V.
// ---------------------------------------------------------------------------
__global__ __launch_bounds__(256) void mqa_attn_bf16(
    const u16* __restrict__ Q, const u16* __restrict__ Kg,
    const u16* __restrict__ Vtg, u16* __restrict__ Ohi, u16* __restrict__ Olo)
{
    __shared__ __align__(16) u16 Ks[64 * 128];
    __shared__ __align__(16) u16 Vt[128 * 64];
    __shared__ __align__(16) u16 Ps[4][16 * 64];

    const int tid = threadIdx.x;
    const int wid = tid >> 6;
    const int lane = tid & 63;
    const int lr = lane & 15;
    const int lhi = lane >> 4;

    const int qt = blockIdx.x;
    const int h  = blockIdx.y;
    const int b  = blockIdx.z;
    const size_t bseq = (size_t)b * SEQ;
    const int q0 = qt * 64 + wid * 16;

    bf16x8 qf[4];
    {
        const u16* qrow = Q + (bseq + q0 + lr) * DIM + (size_t)h * HD;
#pragma unroll
        for (int kk = 0; kk < 4; ++kk)
            qf[kk] = *(const bf16x8*)(qrow + kk * 32 + lhi * 8);
    }

    bf16x8 ones;
#pragma unroll
    for (int j = 0; j < 8; ++j) ones[j] = (short)0x3F80;   // bf16 1.0

    f32x4 o[8];
#pragma unroll
    for (int dt = 0; dt < 8; ++dt) o[dt] = (f32x4){0.f, 0.f, 0.f, 0.f};
    float m[4] = {-INFINITY, -INFINITY, -INFINITY, -INFINITY};
    float lsum[4] = {0.f, 0.f, 0.f, 0.f};

    ushort8v kreg[4], vreg[4];
#define LOAD_KV(t0_)                                                          \
    {                                                                         \
        _Pragma("unroll")                                                     \
        for (int i = 0; i < 4; ++i) {                                         \
            const int idx = tid + i * 256;                                    \
            kreg[i] = *(const ushort8v*)&Kg[(bseq + (t0_) + (idx >> 4)) * HD  \
                                            + (idx & 15) * 8];                \
            vreg[i] = *(const ushort8v*)&Vtg[(size_t)(idx >> 3) * TOKENS      \
                                             + bseq + (t0_) + (idx & 7) * 8]; \
        }                                                                     \
    }

    LOAD_KV(0);

    for (int t0 = 0; t0 < SEQ; t0 += 64) {
        __syncthreads();
#pragma unroll
        for (int i = 0; i < 4; ++i) {
            const int idx = tid + i * 256;
            *(ushort8v*)&Ks[KIDX(idx >> 4, (idx & 15) * 8)] = kreg[i];
            *(ushort8v*)&Vt[VIDX(idx >> 3, (idx & 7) * 8)] = vreg[i];
        }
        __syncthreads();
        if (t0 + 64 < SEQ) LOAD_KV(t0 + 64);

        f32x4 sc[4];
#pragma unroll
        for (int ct = 0; ct < 4; ++ct) sc[ct] = (f32x4){0.f, 0.f, 0.f, 0.f};
        __builtin_amdgcn_s_setprio(1);
#pragma unroll
        for (int kk = 0; kk < 4; ++kk)
#pragma unroll
            for (int ct = 0; ct < 4; ++ct) {
                const bf16x8 kf = *(const bf16x8*)&Ks[KIDX(ct * 16 + lr, kk * 32 + lhi * 8)];
                sc[ct] = __builtin_amdgcn_mfma_f32_16x16x32_bf16(qf[kk], kf, sc[ct], 0, 0, 0);
            }
        __builtin_amdgcn_s_setprio(0);

        float pm[4];
#pragma unroll
        for (int r = 0; r < 4; ++r)
            pm[r] = fmaxf(fmaxf(sc[0][r], sc[1][r]), fmaxf(sc[2][r], sc[3][r]));
#pragma unroll
        for (int msk = 1; msk < 16; msk <<= 1)
#pragma unroll
            for (int r = 0; r < 4; ++r)
                pm[r] = fmaxf(pm[r], __shfl_xor(pm[r], msk, 64));

        float al[4];
        bool need = false;
#pragma unroll
        for (int r = 0; r < 4; ++r) {
            if (pm[r] > m[r] + 8.f) {
                al[r] = __expf(m[r] - pm[r]);
                m[r] = pm[r];
                need = true;
            } else {
                al[r] = 1.f;
            }
        }

#pragma unroll
        for (int ct = 0; ct < 4; ++ct)
#pragma unroll
            for (int r = 0; r < 4; ++r)
                Ps[wid][PIDX(lhi * 4 + r, ct * 16 + lr)] = f2bf(__expf(sc[ct][r] - m[r]));

        if (need) {
#pragma unroll
            for (int dt = 0; dt < 8; ++dt)
#pragma unroll
                for (int r = 0; r < 4; ++r)
                    o[dt][r] *= al[r];
        }

        f32x4 lacc = (f32x4){0.f, 0.f, 0.f, 0.f};
        __builtin_amdgcn_s_setprio(1);
#pragma unroll
        for (int kk = 0; kk < 2; ++kk) {
            const bf16x8 pa = *(const bf16x8*)&Ps[wid][PIDX(lr, kk * 32 + lhi * 8)];
            lacc = __builtin_amdgcn_mfma_f32_16x16x32_bf16(pa, ones, lacc, 0, 0, 0);
#pragma unroll
            for (int dt = 0; dt < 8; ++dt) {
                const bf16x8 vb = *(const bf16x8*)&Vt[VIDX(dt * 16 + lr, kk * 32 + lhi * 8)];
                o[dt] = __builtin_amdgcn_mfma_f32_16x16x32_bf16(pa, vb, o[dt], 0, 0, 0);
            }
        }
        __builtin_amdgcn_s_setprio(0);
#pragma unroll
        for (int r = 0; r < 4; ++r)
            lsum[r] = lsum[r] * al[r] + lacc[r];
    }

#pragma unroll
    for (int r = 0; r < 4; ++r) {
        const float inv = 1.f / lsum[r];
        const size_t base = (bseq + q0 + lhi * 4 + r) * DIM + (size_t)h * HD + lr;
        u16* oph = Ohi + base;
        u16* opl = Olo + base;
#pragma unroll
        for (int dt = 0; dt < 8; ++dt) {
            const float val = o[dt][r] * inv;
            const u16 hv = f2bf(val);
            oph[dt * 16] = hv;
            opl[dt * 16] = f2bf(val - bf2f(hv));
        }
    }
}

// ---------------------------------------------------------------------------
extern "C" void kernel_launch(void* const* d_in, const int* in_sizes, int n_in,
                              void* d_out, int out_size, void* d_ws, size_t ws_size,
                              hipStream_t stream) {
    const float* x  = (const float*)d_in[0];
    const float* wq = (const float*)d_in[1];
    const float* bq = (const float*)d_in[2];
    const float* wk = (const float*)d_in[3];
    const float* bk = (const float*)d_in[4];
    const float* wv = (const float*)d_in[5];
    const float* bv = (const float*)d_in[6];
    const float* wo = (const float*)d_in[7];
    const float* bo = (const float*)d_in[8];
    float* out = (float*)d_out;

    char* w = (char*)d_ws;
    u16* x_hi   = (u16*)w;                 w += (size_t)TOKENS * DIM * 2;
    u16* x_lo   = (u16*)w;                 w += (size_t)TOKENS * DIM * 2;
    u16* wcat_h = (u16*)w;                 w += (size_t)NQKV * DIM * 2;
    u16* wcat_l = (u16*)w;                 w += (size_t)NQKV * DIM * 2;
    u16* wo_h   = (u16*)w;                 w += (size_t)DIM * DIM * 2;
    u16* wo_l   = (u16*)w;                 w += (size_t)DIM * DIM * 2;
    u16* qb     = (u16*)w;                 w += (size_t)TOKENS * DIM * 2;
    u16* kb     = (u16*)w;                 w += (size_t)TOKENS * HD * 2;
    u16* vtb    = (u16*)w;                 w += (size_t)TOKENS * HD * 2;
    float* bc   = (float*)w;               w += 16384;
    u16* Ohi = x_hi;   // x dead after QKV GEMM; stream order makes this safe
    u16* Olo = x_lo;

    const float scale = 0.08838834764831845f;  // 1/sqrt(128)
    const dim3 blk(256);

    split_bf16<<<TOKENS * DIM / 4 / 256, blk, 0, stream>>>(x, x_hi, x_lo);
    transpose_split<<<dim3(DIM / 32, DIM / 32), blk, 0, stream>>>(wq, wcat_h, wcat_l, DIM, DIM, 0);
    transpose_split<<<dim3(DIM / 32, HD / 32), blk, 0, stream>>>(wk, wcat_h, wcat_l, DIM, HD, DIM);
    transpose_split<<<dim3(DIM / 32, HD / 32), blk, 0, stream>>>(wv, wcat_h, wcat_l, DIM, HD, DIM + HD);
    transpose_split<<<dim3(DIM / 32, DIM / 32), blk, 0, stream>>>(wo, wo_h, wo_l, DIM, DIM, 0);
    concat_bias<<<NQKV / 256, blk, 0, stream>>>(bq, bk, bv, bc);

    gemm_split<0><<<dim3(NQKV / 128, TOKENS / 128), blk, 0, stream>>>(
        x_hi, x_lo, wcat_h, wcat_l, bc, nullptr, qb, kb, vtb, scale);

    mqa_attn_bf16<<<dim3(SEQ / 64, NH, BATCH), blk, 0, stream>>>(qb, kb, vtb, Ohi, Olo);

    gemm_split<1><<<dim3(DIM / 128, TOKENS / 128), blk, 0, stream>>>(
        Ohi, Olo, wo_h, wo_l, bo, out, nullptr, nullptr, nullptr, 1.0f);
}

// Round 6
// 379.705 us; speedup vs baseline: 6.0551x; 1.0710x over previous
//
#include <hip/hip_runtime.h>
#include <hip/hip_bf16.h>
#include <math.h>

#define DIM 2048
#define NH 16
#define HD 128
#define BATCH 2
#define SEQ 2048
#define TOKENS (BATCH * SEQ)   // 4096
#define NQKV (DIM + 2 * HD)    // 2304

typedef __attribute__((ext_vector_type(8))) short bf16x8;
typedef __attribute__((ext_vector_type(8))) unsigned short ushort8v;
typedef __attribute__((ext_vector_type(4))) float f32x4;
typedef unsigned short u16;

__device__ __forceinline__ u16 f2bf(float f) {
    union { float f; unsigned int u; } v; v.f = f;
    unsigned int r = (v.u + 0x7FFFu + ((v.u >> 16) & 1u)) >> 16;
    return (u16)r;
}
__device__ __forceinline__ float bf2f(u16 h) {
    union { unsigned int u; float f; } v; v.u = ((unsigned int)h) << 16;
    return v.f;
}
__device__ __forceinline__ void gll16(const void* g, void* l) {
    __builtin_amdgcn_global_load_lds(
        (const __attribute__((address_space(1))) unsigned int*)g,
        (__attribute__((address_space(3))) unsigned int*)l, 16, 0, 0);
}

// K/V LDS layout: linear rows, 16B-chunk XOR-swizzled. Written by
// global_load_lds (linear dest) with INVERSE-swizzled global source chunk;
// read with the same XOR (rule #21 both-sides).
#define KIDX(r, c) ((r) * 128 + (((((c) << 1)) ^ (((r) & 7) << 4)) >> 1))
#define VIDX(d, c) ((d) * 64  + (((((c) << 1)) ^ (((d) & 7) << 4)) >> 1))
// P LDS: rows 0..31, 64 cols; XOR chosen so C-layout scalar writes are
// conflict-free (bank = lr/2 + 8*(ct^lhi^r)) and A-frag reads are 2-way.
#define PIDX(row, col) ((row) * 64 + \
    (((((col) << 1)) ^ (((((row) >> 2) & 3) ^ ((row) & 3)) << 5)) >> 1))

// ---------------------------------------------------------------------------
// prep kernels
// ---------------------------------------------------------------------------
__global__ __launch_bounds__(256) void split_bf16(
    const float* __restrict__ in, u16* __restrict__ hi, u16* __restrict__ lo)
{
    const int i = blockIdx.x * 256 + threadIdx.x;
    const float4 v = ((const float4*)in)[i];
    ushort4 h, l;
    h.x = f2bf(v.x); l.x = f2bf(v.x - bf2f(h.x));
    h.y = f2bf(v.y); l.y = f2bf(v.y - bf2f(h.y));
    h.z = f2bf(v.z); l.z = f2bf(v.z - bf2f(h.z));
    h.w = f2bf(v.w); l.w = f2bf(v.w - bf2f(h.w));
    ((ushort4*)hi)[i] = h;
    ((ushort4*)lo)[i] = l;
}

__global__ __launch_bounds__(256) void transpose_split(
    const float* __restrict__ W, u16* __restrict__ Th, u16* __restrict__ Tl,
    int K, int N, int rowoff)
{
    __shared__ float tile[32][33];
    const int k0 = blockIdx.x * 32;
    const int n0 = blockIdx.y * 32;
    const int tid = threadIdx.x;
#pragma unroll
    for (int i = 0; i < 4; ++i) {
        const int idx = tid + i * 256;
        const int r = idx >> 5, c = idx & 31;
        tile[r][c] = W[(size_t)(k0 + r) * N + n0 + c];
    }
    __syncthreads();
#pragma unroll
    for (int i = 0; i < 4; ++i) {
        const int idx = tid + i * 256;
        const int r = idx >> 5, c = idx & 31;
        const float v = tile[c][r];
        const u16 hv = f2bf(v);
        const size_t off = (size_t)(rowoff + n0 + r) * K + k0 + c;
        Th[off] = hv;
        Tl[off] = f2bf(v - bf2f(hv));
    }
}

__global__ __launch_bounds__(256) void concat_bias(
    const float* __restrict__ bq, const float* __restrict__ bk,
    const float* __restrict__ bv, float* __restrict__ bc)
{
    const int i = blockIdx.x * 256 + threadIdx.x;
    float v;
    if (i < DIM) v = bq[i];
    else if (i < DIM + HD) v = bk[i - DIM];
    else v = bv[i - DIM - HD];
    bc[i] = v;
}

// ---------------------------------------------------------------------------
// Split-bf16 GEMM (3-pass hi/lo), 128x128 tile, BK=32, dbuf + gll (unchanged).
// ---------------------------------------------------------------------------
template <int MODE>
__global__ __launch_bounds__(256) void gemm_split(
    const u16* __restrict__ Ah, const u16* __restrict__ Al,
    const u16* __restrict__ Bh, const u16* __restrict__ Bl,
    const float* __restrict__ bias, float* __restrict__ Cf,
    u16* __restrict__ qdst, u16* __restrict__ kdst, u16* __restrict__ vtdst,
    float scale)
{
    constexpr int BK = 32;
    __shared__ u16 lds[2][4 * 128 * BK];

    const int tid = threadIdx.x;
    const int wid = tid >> 6;
    const int lane = tid & 63;
    const int lr = lane & 15;
    const int lhi = lane >> 4;
    const int wr = wid >> 1, wc = wid & 1;
    const int bm = blockIdx.y * 128;
    const int bn = blockIdx.x * 128;

    f32x4 acc[4][4];
#pragma unroll
    for (int i = 0; i < 4; ++i)
#pragma unroll
        for (int j = 0; j < 4; ++j) acc[i][j] = (f32x4){0.f, 0.f, 0.f, 0.f};

#define STAGE(buf_, k0_)                                                      \
    {                                                                         \
        _Pragma("unroll")                                                     \
        for (int rr = 0; rr < 2; ++rr) {                                      \
            const int slot = rr * 256 + tid;                                  \
            const int row = slot >> 2;                                        \
            const int gch = ((slot & 3) ^ ((row >> 1) & 3)) * 8;              \
            char* lbase = (char*)lds[buf_] + (size_t)(rr * 256 + wid * 64) * 16; \
            const size_t ga = (size_t)(bm + row) * DIM + (k0_) + gch;         \
            const size_t gb = (size_t)(bn + row) * DIM + (k0_) + gch;         \
            gll16(Ah + ga, lbase);                                            \
            gll16(Al + ga, lbase + 8192);                                     \
            gll16(Bh + gb, lbase + 16384);                                    \
            gll16(Bl + gb, lbase + 24576);                                    \
        }                                                                     \
    }

    STAGE(0, 0);
    __syncthreads();

    int cur = 0;
    for (int k0 = 0; k0 < DIM; k0 += BK) {
        if (k0 + BK < DIM) STAGE(cur ^ 1, k0 + BK);

        bf16x8 ah[4], al[4], bh[4], bl[4];
#pragma unroll
        for (int i = 0; i < 4; ++i) {
            const int mrow = wr * 64 + i * 16 + lr;
            const int nrow = wc * 64 + i * 16 + lr;
            const int mo = mrow * BK + ((lhi ^ ((mrow >> 1) & 3)) * 8);
            const int no = nrow * BK + ((lhi ^ ((nrow >> 1) & 3)) * 8);
            ah[i] = *(const bf16x8*)&lds[cur][mo];
            al[i] = *(const bf16x8*)&lds[cur][4096 + mo];
            bh[i] = *(const bf16x8*)&lds[cur][8192 + no];
            bl[i] = *(const bf16x8*)&lds[cur][12288 + no];
        }
        __builtin_amdgcn_s_setprio(1);
#pragma unroll
        for (int i = 0; i < 4; ++i)
#pragma unroll
            for (int j = 0; j < 4; ++j) {
                acc[i][j] = __builtin_amdgcn_mfma_f32_16x16x32_bf16(ah[i], bh[j], acc[i][j], 0, 0, 0);
                acc[i][j] = __builtin_amdgcn_mfma_f32_16x16x32_bf16(ah[i], bl[j], acc[i][j], 0, 0, 0);
                acc[i][j] = __builtin_amdgcn_mfma_f32_16x16x32_bf16(al[i], bh[j], acc[i][j], 0, 0, 0);
            }
        __builtin_amdgcn_s_setprio(0);
        __syncthreads();
        cur ^= 1;
    }
#undef STAGE

    const float alpha = (MODE == 0 && bn < DIM) ? scale : 1.0f;
    float bj[4];
#pragma unroll
    for (int j = 0; j < 4; ++j) bj[j] = bias[bn + wc * 64 + j * 16 + lr];

#pragma unroll
    for (int i = 0; i < 4; ++i) {
#pragma unroll
        for (int j = 0; j < 4; ++j) {
#pragma unroll
            for (int r = 0; r < 4; ++r) {
                const int row = bm + wr * 64 + i * 16 + lhi * 4 + r;
                const int col = bn + wc * 64 + j * 16 + lr;
                const float val = (acc[i][j][r] + bj[j]) * alpha;
                if (MODE == 1) {
                    Cf[(size_t)row * DIM + col] = val;
                } else if (bn < DIM) {
                    qdst[(size_t)row * DIM + col] = f2bf(val);
                } else if (bn < DIM + HD) {
                    kdst[(size_t)row * HD + (col - DIM)] = f2bf(val);
                } else {
                    vtdst[(size_t)(col - DIM - HD) * TOKENS + row] = f2bf(val);
                }
            }
        }
    }
}

// ---------------------------------------------------------------------------
// MQA flash attention. BQ=128 (4 waves x 32 q-rows, 2 m-tiles/wave), BT=64.
// K/V double-buffered in LDS, staged by global_load_lds with pre-swizzled
// source; every kf/vb LDS read feeds 2 MFMAs.
// ---------------------------------------------------------------------------
__global__ __launch_bounds__(256, 2) void mqa_attn_bf16(
    const u16* __restrict__ Q, const u16* __restrict__ Kg,
    const u16* __restrict__ Vtg, u16* __restrict__ Ohi, u16* __restrict__ Olo)
{
    __shared__ __align__(16) u16 Ks[2][64 * 128];   // 32 KB
    __shared__ __align__(16) u16 Vt[2][128 * 64];   // 32 KB
    __shared__ __align__(16) u16 Ps[4][32 * 64];    // 16 KB (per-wave)

    const int tid = threadIdx.x;
    const int wid = tid >> 6;
    const int lane = tid & 63;
    const int lr = lane & 15;
    const int lhi = lane >> 4;

    const int qt = blockIdx.x;
    const int h  = blockIdx.y;
    const int b  = blockIdx.z;
    const size_t bseq = (size_t)b * SEQ;
    const int q0 = qt * 128 + wid * 32;

    // Q fragments: 2 m-tiles x 4 k-chunks
    bf16x8 qf[2][4];
#pragma unroll
    for (int mt = 0; mt < 2; ++mt) {
        const u16* qrow = Q + (bseq + q0 + mt * 16 + lr) * DIM + (size_t)h * HD;
#pragma unroll
        for (int kk = 0; kk < 4; ++kk)
            qf[mt][kk] = *(const bf16x8*)(qrow + kk * 32 + lhi * 8);
    }

    bf16x8 ones;
#pragma unroll
    for (int j = 0; j < 8; ++j) ones[j] = (short)0x3F80;   // bf16 1.0

    f32x4 o[2][8];
#pragma unroll
    for (int mt = 0; mt < 2; ++mt)
#pragma unroll
        for (int dt = 0; dt < 8; ++dt) o[mt][dt] = (f32x4){0.f, 0.f, 0.f, 0.f};
    float m[2][4], lsum[2][4];
#pragma unroll
    for (int mt = 0; mt < 2; ++mt)
#pragma unroll
        for (int r = 0; r < 4; ++r) { m[mt][r] = -INFINITY; lsum[mt][r] = 0.f; }

    // stage K (64x128) + V^T (128x64) tiles via global_load_lds; LDS dest
    // linear (wave-uniform base + lane*16), source chunk pre-swizzled to
    // match KIDX/VIDX read XOR.
#define STAGE_KV(buf_, t0_)                                                   \
    {                                                                         \
        _Pragma("unroll")                                                     \
        for (int i = 0; i < 4; ++i) {                                         \
            const int L = i * 256 + tid;                                      \
            char* kbase = (char*)&Ks[buf_][0] + (size_t)(i * 256 + wid * 64) * 16; \
            char* vbase = (char*)&Vt[buf_][0] + (size_t)(i * 256 + wid * 64) * 16; \
            const int krow = L >> 4, kc = (L & 15) ^ ((L >> 4) & 7);          \
            const int vrow = L >> 3, vc = (L & 7) ^ ((L >> 3) & 7);           \
            gll16(&Kg[(bseq + (t0_) + krow) * HD + kc * 8], kbase);           \
            gll16(&Vtg[(size_t)vrow * TOKENS + bseq + (t0_) + vc * 8], vbase);\
        }                                                                     \
    }

    STAGE_KV(0, 0);
    __syncthreads();

    int cur = 0;
    for (int t0 = 0; t0 < SEQ; t0 += 64) {
        if (t0 + 64 < SEQ) STAGE_KV(cur ^ 1, t0 + 64);   // prefetch under compute

        // ---- QK^T: 16 kf reads feed 32 MFMAs ----
        f32x4 sc[2][4];
#pragma unroll
        for (int mt = 0; mt < 2; ++mt)
#pragma unroll
            for (int ct = 0; ct < 4; ++ct) sc[mt][ct] = (f32x4){0.f, 0.f, 0.f, 0.f};
        __builtin_amdgcn_s_setprio(1);
#pragma unroll
        for (int kk = 0; kk < 4; ++kk)
#pragma unroll
            for (int ct = 0; ct < 4; ++ct) {
                const bf16x8 kf = *(const bf16x8*)&Ks[cur][KIDX(ct * 16 + lr, kk * 32 + lhi * 8)];
                sc[0][ct] = __builtin_amdgcn_mfma_f32_16x16x32_bf16(qf[0][kk], kf, sc[0][ct], 0, 0, 0);
                sc[1][ct] = __builtin_amdgcn_mfma_f32_16x16x32_bf16(qf[1][kk], kf, sc[1][ct], 0, 0, 0);
            }
        __builtin_amdgcn_s_setprio(0);

        // ---- online softmax (defer-max THR=8), per m-tile ----
        float al[2][4];
        bool need[2] = {false, false};
#pragma unroll
        for (int mt = 0; mt < 2; ++mt) {
            float pm[4];
#pragma unroll
            for (int r = 0; r < 4; ++r)
                pm[r] = fmaxf(fmaxf(sc[mt][0][r], sc[mt][1][r]),
                              fmaxf(sc[mt][2][r], sc[mt][3][r]));
#pragma unroll
            for (int msk = 1; msk < 16; msk <<= 1)
#pragma unroll
                for (int r = 0; r < 4; ++r)
                    pm[r] = fmaxf(pm[r], __shfl_xor(pm[r], msk, 64));
#pragma unroll
            for (int r = 0; r < 4; ++r) {
                if (pm[r] > m[mt][r] + 8.f) {
                    al[mt][r] = __expf(m[mt][r] - pm[r]);
                    m[mt][r] = pm[r];
                    need[mt] = true;
                } else {
                    al[mt][r] = 1.f;
                }
            }
#pragma unroll
            for (int ct = 0; ct < 4; ++ct)
#pragma unroll
                for (int r = 0; r < 4; ++r)
                    Ps[wid][PIDX(mt * 16 + lhi * 4 + r, ct * 16 + lr)] =
                        f2bf(__expf(sc[mt][ct][r] - m[mt][r]));
            if (need[mt]) {
#pragma unroll
                for (int dt = 0; dt < 8; ++dt)
#pragma unroll
                    for (int r = 0; r < 4; ++r)
                        o[mt][dt][r] *= al[mt][r];
            }
        }

        // ---- PV + row-sum: 16 vb + 4 pa reads feed 36 MFMAs ----
        f32x4 lacc[2];
        lacc[0] = (f32x4){0.f, 0.f, 0.f, 0.f};
        lacc[1] = (f32x4){0.f, 0.f, 0.f, 0.f};
        __builtin_amdgcn_s_setprio(1);
#pragma unroll
        for (int kk = 0; kk < 2; ++kk) {
            const bf16x8 pa0 = *(const bf16x8*)&Ps[wid][PIDX(lr, kk * 32 + lhi * 8)];
            const bf16x8 pa1 = *(const bf16x8*)&Ps[wid][PIDX(16 + lr, kk * 32 + lhi * 8)];
            lacc[0] = __builtin_amdgcn_mfma_f32_16x16x32_bf16(pa0, ones, lacc[0], 0, 0, 0);
            lacc[1] = __builtin_amdgcn_mfma_f32_16x16x32_bf16(pa1, ones, lacc[1], 0, 0, 0);
#pragma unroll
            for (int dt = 0; dt < 8; ++dt) {
                const bf16x8 vb = *(const bf16x8*)&Vt[cur][VIDX(dt * 16 + lr, kk * 32 + lhi * 8)];
                o[0][dt] = __builtin_amdgcn_mfma_f32_16x16x32_bf16(pa0, vb, o[0][dt], 0, 0, 0);
                o[1][dt] = __builtin_amdgcn_mfma_f32_16x16x32_bf16(pa1, vb, o[1][dt], 0, 0, 0);
            }
        }
        __builtin_amdgcn_s_setprio(0);
#pragma unroll
        for (int mt = 0; mt < 2; ++mt)
#pragma unroll
            for (int r = 0; r < 4; ++r)
                lsum[mt][r] = lsum[mt][r] * al[mt][r] + lacc[mt][r];

        __syncthreads();   // drains prefetch vmcnt; releases read buffer
        cur ^= 1;
    }
#undef STAGE_KV

    // ---- epilogue: normalize, split-write bf16 hi/lo ----
#pragma unroll
    for (int mt = 0; mt < 2; ++mt)
#pragma unroll
        for (int r = 0; r < 4; ++r) {
            const float inv = 1.f / lsum[mt][r];
            const size_t base =
                (bseq + q0 + mt * 16 + lhi * 4 + r) * DIM + (size_t)h * HD + lr;
            u16* oph = Ohi + base;
            u16* opl = Olo + base;
#pragma unroll
            for (int dt = 0; dt < 8; ++dt) {
                const float val = o[mt][dt][r] * inv;
                const u16 hv = f2bf(val);
                oph[dt * 16] = hv;
                opl[dt * 16] = f2bf(val - bf2f(hv));
            }
        }
}

// ---------------------------------------------------------------------------
extern "C" void kernel_launch(void* const* d_in, const int* in_sizes, int n_in,
                              void* d_out, int out_size, void* d_ws, size_t ws_size,
                              hipStream_t stream) {
    const float* x  = (const float*)d_in[0];
    const float* wq = (const float*)d_in[1];
    const float* bq = (const float*)d_in[2];
    const float* wk = (const float*)d_in[3];
    const float* bk = (const float*)d_in[4];
    const float* wv = (const float*)d_in[5];
    const float* bv = (const float*)d_in[6];
    const float* wo = (const float*)d_in[7];
    const float* bo = (const float*)d_in[8];
    float* out = (float*)d_out;

    char* w = (char*)d_ws;
    u16* x_hi   = (u16*)w;                 w += (size_t)TOKENS * DIM * 2;
    u16* x_lo   = (u16*)w;                 w += (size_t)TOKENS * DIM * 2;
    u16* wcat_h = (u16*)w;                 w += (size_t)NQKV * DIM * 2;
    u16* wcat_l = (u16*)w;                 w += (size_t)NQKV * DIM * 2;
    u16* wo_h   = (u16*)w;                 w += (size_t)DIM * DIM * 2;
    u16* wo_l   = (u16*)w;                 w += (size_t)DIM * DIM * 2;
    u16* qb     = (u16*)w;                 w += (size_t)TOKENS * DIM * 2;
    u16* kb     = (u16*)w;                 w += (size_t)TOKENS * HD * 2;
    u16* vtb    = (u16*)w;                 w += (size_t)TOKENS * HD * 2;
    float* bc   = (float*)w;               w += 16384;
    u16* Ohi = x_hi;   // x dead after QKV GEMM; stream order makes this safe
    u16* Olo = x_lo;

    const float scale = 0.08838834764831845f;  // 1/sqrt(128)
    const dim3 blk(256);

    split_bf16<<<TOKENS * DIM / 4 / 256, blk, 0, stream>>>(x, x_hi, x_lo);
    transpose_split<<<dim3(DIM / 32, DIM / 32), blk, 0, stream>>>(wq, wcat_h, wcat_l, DIM, DIM, 0);
    transpose_split<<<dim3(DIM / 32, HD / 32), blk, 0, stream>>>(wk, wcat_h, wcat_l, DIM, HD, DIM);
    transpose_split<<<dim3(DIM / 32, HD / 32), blk, 0, stream>>>(wv, wcat_h, wcat_l, DIM, HD, DIM + HD);
    transpose_split<<<dim3(DIM / 32, DIM / 32), blk, 0, stream>>>(wo, wo_h, wo_l, DIM, DIM, 0);
    concat_bias<<<NQKV / 256, blk, 0, stream>>>(bq, bk, bv, bc);

    gemm_split<0><<<dim3(NQKV / 128, TOKENS / 128), blk, 0, stream>>>(
        x_hi, x_lo, wcat_h, wcat_l, bc, nullptr, qb, kb, vtb, scale);

    mqa_attn_bf16<<<dim3(SEQ / 128, NH, BATCH), blk, 0, stream>>>(qb, kb, vtb, Ohi, Olo);

    gemm_split<1><<<dim3(DIM / 128, TOKENS / 128), blk, 0, stream>>>(
        Ohi, Olo, wo_h, wo_l, bo, out, nullptr, nullptr, nullptr, 1.0f);
}

// Round 7
// 245.952 us; speedup vs baseline: 9.3480x; 1.5438x over previous
//
#include <hip/hip_runtime.h>
#include <hip/hip_bf16.h>
#include <math.h>

#define DIM 2048
#define NH 16
#define HD 128
#define BATCH 2
#define SEQ 2048
#define TOKENS (BATCH * SEQ)   // 4096
#define NQKV (DIM + 2 * HD)    // 2304

typedef __attribute__((ext_vector_type(8))) _Float16 f16x8;
typedef __attribute__((ext_vector_type(4))) float f32x4;
typedef unsigned short u16;

__device__ __forceinline__ u16 f2h(float f) {
    union { _Float16 h; u16 u; } v; v.h = (_Float16)f; return v.u;
}
__device__ __forceinline__ void gll16(const void* g, void* l) {
    __builtin_amdgcn_global_load_lds(
        (const __attribute__((address_space(1))) unsigned int*)g,
        (__attribute__((address_space(3))) unsigned int*)l, 16, 0, 0);
}

// K/V LDS layout: linear rows, 16B-chunk XOR-swizzled; written by
// global_load_lds (linear dest) with inverse-swizzled global source chunk;
// read with the same XOR (rule #21 both-sides).
#define KIDX(r, c) ((r) * 128 + (((((c) << 1)) ^ (((r) & 7) << 4)) >> 1))
#define VIDX(d, c) ((d) * 64  + (((((c) << 1)) ^ (((d) & 7) << 4)) >> 1))
// P LDS: conflict-free scalar C-layout writes, 2-way A-frag reads.
#define PIDX(row, col) ((row) * 64 + \
    (((((col) << 1)) ^ (((((row) >> 2) & 3) ^ ((row) & 3)) << 5)) >> 1))

// ---------------------------------------------------------------------------
// prep kernels
// ---------------------------------------------------------------------------
__global__ __launch_bounds__(256) void conv_f16(
    const float* __restrict__ in, u16* __restrict__ out)
{
    const int i = blockIdx.x * 256 + threadIdx.x;
    const float4 v = ((const float4*)in)[i];
    ushort4 h;
    h.x = f2h(v.x); h.y = f2h(v.y); h.z = f2h(v.z); h.w = f2h(v.w);
    ((ushort4*)out)[i] = h;
}

__global__ __launch_bounds__(256) void transpose_f16(
    const float* __restrict__ W, u16* __restrict__ T, int K, int N, int rowoff)
{
    __shared__ float tile[32][33];
    const int k0 = blockIdx.x * 32;
    const int n0 = blockIdx.y * 32;
    const int tid = threadIdx.x;
#pragma unroll
    for (int i = 0; i < 4; ++i) {
        const int idx = tid + i * 256;
        const int r = idx >> 5, c = idx & 31;
        tile[r][c] = W[(size_t)(k0 + r) * N + n0 + c];
    }
    __syncthreads();
#pragma unroll
    for (int i = 0; i < 4; ++i) {
        const int idx = tid + i * 256;
        const int r = idx >> 5, c = idx & 31;
        T[(size_t)(rowoff + n0 + r) * K + k0 + c] = f2h(tile[c][r]);
    }
}

__global__ __launch_bounds__(256) void concat_bias(
    const float* __restrict__ bq, const float* __restrict__ bk,
    const float* __restrict__ bv, float* __restrict__ bc)
{
    const int i = blockIdx.x * 256 + threadIdx.x;
    float v;
    if (i < DIM) v = bq[i];
    else if (i < DIM + HD) v = bk[i - DIM];
    else v = bv[i - DIM - HD];
    bc[i] = v;
}

// ---------------------------------------------------------------------------
// fp16 GEMM: C = A[M,2048] @ B^T + bias.  B: [Nrows][2048] fp16 (row n =
// col n of W).  128x128 tile, BK=32, 4 waves, dbuf LDS + global_load_lds,
// source-chunk swizzle (conflict-free, verified round 6: SQ_LDS_BANK_CONFLICT=0).
// MODE 0: QKV epilogue (q fp16 scaled | k fp16 | v^T fp16); MODE 1: f32 out.
// ---------------------------------------------------------------------------
template <int MODE>
__global__ __launch_bounds__(256) void gemm_f16(
    const u16* __restrict__ A, const u16* __restrict__ B,
    const float* __restrict__ bias, float* __restrict__ Cf,
    u16* __restrict__ qdst, u16* __restrict__ kdst, u16* __restrict__ vtdst,
    float scale)
{
    constexpr int BK = 32;
    __shared__ u16 lds[2][2 * 128 * BK];   // A | B : 8 KB each; 32 KB total

    const int tid = threadIdx.x;
    const int wid = tid >> 6;
    const int lane = tid & 63;
    const int lr = lane & 15;
    const int lhi = lane >> 4;
    const int wr = wid >> 1, wc = wid & 1;
    const int bm = blockIdx.y * 128;
    const int bn = blockIdx.x * 128;

    f32x4 acc[4][4];
#pragma unroll
    for (int i = 0; i < 4; ++i)
#pragma unroll
        for (int j = 0; j < 4; ++j) acc[i][j] = (f32x4){0.f, 0.f, 0.f, 0.f};

#define STAGE(buf_, k0_)                                                      \
    {                                                                         \
        _Pragma("unroll")                                                     \
        for (int rr = 0; rr < 2; ++rr) {                                      \
            const int slot = rr * 256 + tid;                                  \
            const int row = slot >> 2;                                        \
            const int gch = ((slot & 3) ^ ((row >> 1) & 3)) * 8;              \
            char* lbase = (char*)lds[buf_] + (size_t)(rr * 256 + wid * 64) * 16; \
            gll16(A + (size_t)(bm + row) * DIM + (k0_) + gch, lbase);         \
            gll16(B + (size_t)(bn + row) * DIM + (k0_) + gch, lbase + 8192);  \
        }                                                                     \
    }

    STAGE(0, 0);
    __syncthreads();

    int cur = 0;
    for (int k0 = 0; k0 < DIM; k0 += BK) {
        if (k0 + BK < DIM) STAGE(cur ^ 1, k0 + BK);   // prefetch under compute

        f16x8 a[4], b[4];
#pragma unroll
        for (int i = 0; i < 4; ++i) {
            const int mrow = wr * 64 + i * 16 + lr;
            const int nrow = wc * 64 + i * 16 + lr;
            a[i] = *(const f16x8*)&lds[cur][mrow * BK + ((lhi ^ ((mrow >> 1) & 3)) * 8)];
            b[i] = *(const f16x8*)&lds[cur][4096 + nrow * BK + ((lhi ^ ((nrow >> 1) & 3)) * 8)];
        }
        __builtin_amdgcn_s_setprio(1);
#pragma unroll
        for (int i = 0; i < 4; ++i)
#pragma unroll
            for (int j = 0; j < 4; ++j)
                acc[i][j] = __builtin_amdgcn_mfma_f32_16x16x32_f16(a[i], b[j], acc[i][j], 0, 0, 0);
        __builtin_amdgcn_s_setprio(0);
        __syncthreads();
        cur ^= 1;
    }
#undef STAGE

    const float alpha = (MODE == 0 && bn < DIM) ? scale : 1.0f;
    float bj[4];
#pragma unroll
    for (int j = 0; j < 4; ++j) bj[j] = bias[bn + wc * 64 + j * 16 + lr];

#pragma unroll
    for (int i = 0; i < 4; ++i) {
#pragma unroll
        for (int j = 0; j < 4; ++j) {
#pragma unroll
            for (int r = 0; r < 4; ++r) {
                const int row = bm + wr * 64 + i * 16 + lhi * 4 + r;
                const int col = bn + wc * 64 + j * 16 + lr;
                const float val = (acc[i][j][r] + bj[j]) * alpha;
                if (MODE == 1) {
                    Cf[(size_t)row * DIM + col] = val;
                } else if (bn < DIM) {
                    qdst[(size_t)row * DIM + col] = f2h(val);
                } else if (bn < DIM + HD) {
                    kdst[(size_t)row * HD + (col - DIM)] = f2h(val);
                } else {
                    vtdst[(size_t)(col - DIM - HD) * TOKENS + row] = f2h(val);
                }
            }
        }
    }
}

// ---------------------------------------------------------------------------
// MQA flash attention, fp16 MFMA. BQ=128 (4 waves x 32 q-rows), BT=64.
// K/V double-buffered LDS via global_load_lds w/ pre-swizzled source.
// ---------------------------------------------------------------------------
__global__ __launch_bounds__(256, 2) void mqa_attn_f16(
    const u16* __restrict__ Q, const u16* __restrict__ Kg,
    const u16* __restrict__ Vtg, u16* __restrict__ Oh)
{
    __shared__ __align__(16) u16 Ks[2][64 * 128];   // 32 KB
    __shared__ __align__(16) u16 Vt[2][128 * 64];   // 32 KB
    __shared__ __align__(16) u16 Ps[4][32 * 64];    // 16 KB (per-wave)

    const int tid = threadIdx.x;
    const int wid = tid >> 6;
    const int lane = tid & 63;
    const int lr = lane & 15;
    const int lhi = lane >> 4;

    const int qt = blockIdx.x;
    const int h  = blockIdx.y;
    const int b  = blockIdx.z;
    const size_t bseq = (size_t)b * SEQ;
    const int q0 = qt * 128 + wid * 32;

    f16x8 qf[2][4];
#pragma unroll
    for (int mt = 0; mt < 2; ++mt) {
        const u16* qrow = Q + (bseq + q0 + mt * 16 + lr) * DIM + (size_t)h * HD;
#pragma unroll
        for (int kk = 0; kk < 4; ++kk)
            qf[mt][kk] = *(const f16x8*)(qrow + kk * 32 + lhi * 8);
    }

    f16x8 ones;
#pragma unroll
    for (int j = 0; j < 8; ++j) ones[j] = (_Float16)1.0f;

    f32x4 o[2][8];
#pragma unroll
    for (int mt = 0; mt < 2; ++mt)
#pragma unroll
        for (int dt = 0; dt < 8; ++dt) o[mt][dt] = (f32x4){0.f, 0.f, 0.f, 0.f};
    float m[2][4], lsum[2][4];
#pragma unroll
    for (int mt = 0; mt < 2; ++mt)
#pragma unroll
        for (int r = 0; r < 4; ++r) { m[mt][r] = -INFINITY; lsum[mt][r] = 0.f; }

#define STAGE_KV(buf_, t0_)                                                   \
    {                                                                         \
        _Pragma("unroll")                                                     \
        for (int i = 0; i < 4; ++i) {                                         \
            const int L = i * 256 + tid;                                      \
            char* kbase = (char*)&Ks[buf_][0] + (size_t)(i * 256 + wid * 64) * 16; \
            char* vbase = (char*)&Vt[buf_][0] + (size_t)(i * 256 + wid * 64) * 16; \
            const int krow = L >> 4, kc = (L & 15) ^ ((L >> 4) & 7);          \
            const int vrow = L >> 3, vc = (L & 7) ^ ((L >> 3) & 7);           \
            gll16(&Kg[(bseq + (t0_) + krow) * HD + kc * 8], kbase);           \
            gll16(&Vtg[(size_t)vrow * TOKENS + bseq + (t0_) + vc * 8], vbase);\
        }                                                                     \
    }

    STAGE_KV(0, 0);
    __syncthreads();

    int cur = 0;
    for (int t0 = 0; t0 < SEQ; t0 += 64) {
        if (t0 + 64 < SEQ) STAGE_KV(cur ^ 1, t0 + 64);

        // ---- QK^T ----
        f32x4 sc[2][4];
#pragma unroll
        for (int mt = 0; mt < 2; ++mt)
#pragma unroll
            for (int ct = 0; ct < 4; ++ct) sc[mt][ct] = (f32x4){0.f, 0.f, 0.f, 0.f};
        __builtin_amdgcn_s_setprio(1);
#pragma unroll
        for (int kk = 0; kk < 4; ++kk)
#pragma unroll
            for (int ct = 0; ct < 4; ++ct) {
                const f16x8 kf = *(const f16x8*)&Ks[cur][KIDX(ct * 16 + lr, kk * 32 + lhi * 8)];
                sc[0][ct] = __builtin_amdgcn_mfma_f32_16x16x32_f16(qf[0][kk], kf, sc[0][ct], 0, 0, 0);
                sc[1][ct] = __builtin_amdgcn_mfma_f32_16x16x32_f16(qf[1][kk], kf, sc[1][ct], 0, 0, 0);
            }
        __builtin_amdgcn_s_setprio(0);

        // ---- online softmax (defer-max THR=8) ----
        float al[2][4];
        bool need[2] = {false, false};
#pragma unroll
        for (int mt = 0; mt < 2; ++mt) {
            float pm[4];
#pragma unroll
            for (int r = 0; r < 4; ++r)
                pm[r] = fmaxf(fmaxf(sc[mt][0][r], sc[mt][1][r]),
                              fmaxf(sc[mt][2][r], sc[mt][3][r]));
#pragma unroll
            for (int msk = 1; msk < 16; msk <<= 1)
#pragma unroll
                for (int r = 0; r < 4; ++r)
                    pm[r] = fmaxf(pm[r], __shfl_xor(pm[r], msk, 64));
#pragma unroll
            for (int r = 0; r < 4; ++r) {
                if (pm[r] > m[mt][r] + 8.f) {
                    al[mt][r] = __expf(m[mt][r] - pm[r]);
                    m[mt][r] = pm[r];
                    need[mt] = true;
                } else {
                    al[mt][r] = 1.f;
                }
            }
#pragma unroll
            for (int ct = 0; ct < 4; ++ct)
#pragma unroll
                for (int r = 0; r < 4; ++r)
                    Ps[wid][PIDX(mt * 16 + lhi * 4 + r, ct * 16 + lr)] =
                        f2h(__expf(sc[mt][ct][r] - m[mt][r]));
            if (need[mt]) {
#pragma unroll
                for (int dt = 0; dt < 8; ++dt)
#pragma unroll
                    for (int r = 0; r < 4; ++r)
                        o[mt][dt][r] *= al[mt][r];
            }
        }

        // ---- PV + row-sum via ones-MFMA ----
        f32x4 lacc[2];
        lacc[0] = (f32x4){0.f, 0.f, 0.f, 0.f};
        lacc[1] = (f32x4){0.f, 0.f, 0.f, 0.f};
        __builtin_amdgcn_s_setprio(1);
#pragma unroll
        for (int kk = 0; kk < 2; ++kk) {
            const f16x8 pa0 = *(const f16x8*)&Ps[wid][PIDX(lr, kk * 32 + lhi * 8)];
            const f16x8 pa1 = *(const f16x8*)&Ps[wid][PIDX(16 + lr, kk * 32 + lhi * 8)];
            lacc[0] = __builtin_amdgcn_mfma_f32_16x16x32_f16(pa0, ones, lacc[0], 0, 0, 0);
            lacc[1] = __builtin_amdgcn_mfma_f32_16x16x32_f16(pa1, ones, lacc[1], 0, 0, 0);
#pragma unroll
            for (int dt = 0; dt < 8; ++dt) {
                const f16x8 vb = *(const f16x8*)&Vt[cur][VIDX(dt * 16 + lr, kk * 32 + lhi * 8)];
                o[0][dt] = __builtin_amdgcn_mfma_f32_16x16x32_f16(pa0, vb, o[0][dt], 0, 0, 0);
                o[1][dt] = __builtin_amdgcn_mfma_f32_16x16x32_f16(pa1, vb, o[1][dt], 0, 0, 0);
            }
        }
        __builtin_amdgcn_s_setprio(0);
#pragma unroll
        for (int mt = 0; mt < 2; ++mt)
#pragma unroll
            for (int r = 0; r < 4; ++r)
                lsum[mt][r] = lsum[mt][r] * al[mt][r] + lacc[mt][r];

        __syncthreads();   // drains prefetch vmcnt; releases read buffer
        cur ^= 1;
    }
#undef STAGE_KV

    // ---- epilogue: normalize, store fp16 ----
#pragma unroll
    for (int mt = 0; mt < 2; ++mt)
#pragma unroll
        for (int r = 0; r < 4; ++r) {
            const float inv = 1.f / lsum[mt][r];
            u16* op = Oh + (bseq + q0 + mt * 16 + lhi * 4 + r) * DIM
                         + (size_t)h * HD + lr;
#pragma unroll
            for (int dt = 0; dt < 8; ++dt)
                op[dt * 16] = f2h(o[mt][dt][r] * inv);
        }
}

// ---------------------------------------------------------------------------
extern "C" void kernel_launch(void* const* d_in, const int* in_sizes, int n_in,
                              void* d_out, int out_size, void* d_ws, size_t ws_size,
                              hipStream_t stream) {
    const float* x  = (const float*)d_in[0];
    const float* wq = (const float*)d_in[1];
    const float* bq = (const float*)d_in[2];
    const float* wk = (const float*)d_in[3];
    const float* bk = (const float*)d_in[4];
    const float* wv = (const float*)d_in[5];
    const float* bv = (const float*)d_in[6];
    const float* wo = (const float*)d_in[7];
    const float* bo = (const float*)d_in[8];
    float* out = (float*)d_out;

    char* w = (char*)d_ws;
    u16* xh     = (u16*)w;                 w += (size_t)TOKENS * DIM * 2;   // 16 MB
    u16* wcat   = (u16*)w;                 w += (size_t)NQKV * DIM * 2;     // 9.4 MB
    u16* woT    = (u16*)w;                 w += (size_t)DIM * DIM * 2;      // 8 MB
    u16* qb     = (u16*)w;                 w += (size_t)TOKENS * DIM * 2;   // 16 MB
    u16* kb     = (u16*)w;                 w += (size_t)TOKENS * HD * 2;    // 1 MB
    u16* vtb    = (u16*)w;                 w += (size_t)TOKENS * HD * 2;    // 1 MB
    float* bc   = (float*)w;               w += 16384;
    u16* Oh = xh;   // x dead after QKV GEMM; stream order makes this safe

    const float scale = 0.08838834764831845f;  // 1/sqrt(128)
    const dim3 blk(256);

    conv_f16<<<TOKENS * DIM / 4 / 256, blk, 0, stream>>>(x, xh);
    transpose_f16<<<dim3(DIM / 32, DIM / 32), blk, 0, stream>>>(wq, wcat, DIM, DIM, 0);
    transpose_f16<<<dim3(DIM / 32, HD / 32), blk, 0, stream>>>(wk, wcat, DIM, HD, DIM);
    transpose_f16<<<dim3(DIM / 32, HD / 32), blk, 0, stream>>>(wv, wcat, DIM, HD, DIM + HD);
    transpose_f16<<<dim3(DIM / 32, DIM / 32), blk, 0, stream>>>(wo, woT, DIM, DIM, 0);
    concat_bias<<<NQKV / 256, blk, 0, stream>>>(bq, bk, bv, bc);

    gemm_f16<0><<<dim3(NQKV / 128, TOKENS / 128), blk, 0, stream>>>(
        xh, wcat, bc, nullptr, qb, kb, vtb, scale);

    mqa_attn_f16<<<dim3(SEQ / 128, NH, BATCH), blk, 0, stream>>>(qb, kb, vtb, Oh);

    gemm_f16<1><<<dim3(DIM / 128, TOKENS / 128), blk, 0, stream>>>(
        Oh, woT, bo, out, nullptr, nullptr, nullptr, 1.0f);
}

// Round 8
// 224.581 us; speedup vs baseline: 10.2375x; 1.0952x over previous
//
#include <hip/hip_runtime.h>
#include <hip/hip_bf16.h>
#include <math.h>

#define DIM 2048
#define NH 16
#define HD 128
#define BATCH 2
#define SEQ 2048
#define TOKENS (BATCH * SEQ)   // 4096
#define NQKV (DIM + 2 * HD)    // 2304

typedef __attribute__((ext_vector_type(8))) _Float16 f16x8;
typedef __attribute__((ext_vector_type(2))) _Float16 f16x2;
typedef __attribute__((ext_vector_type(4))) float f32x4;
typedef unsigned short u16;
typedef unsigned int u32;

typedef union { u32 d[4]; f16x8 v; } frag_u;

__device__ __forceinline__ u16 f2h(float f) {
    union { _Float16 h; u16 u; } v; v.h = (_Float16)f; return v.u;
}
__device__ __forceinline__ void gll16(const void* g, void* l) {
    __builtin_amdgcn_global_load_lds(
        (const __attribute__((address_space(1))) unsigned int*)g,
        (__attribute__((address_space(3))) unsigned int*)l, 16, 0, 0);
}

// K/V LDS layout: linear rows, 16B-chunk XOR-swizzled; written by
// global_load_lds (linear dest) with inverse-swizzled global source chunk;
// read with the same XOR (rule #21 both-sides).
#define KIDX(r, c) ((r) * 128 + (((((c) << 1)) ^ (((r) & 7) << 4)) >> 1))
#define VIDX(d, c) ((d) * 64  + (((((c) << 1)) ^ (((d) & 7) << 4)) >> 1))

// ---------------------------------------------------------------------------
// prep kernels
// ---------------------------------------------------------------------------
__global__ __launch_bounds__(256) void conv_f16(
    const float* __restrict__ in, u16* __restrict__ out)
{
    const int i = blockIdx.x * 256 + threadIdx.x;
    const float4 v = ((const float4*)in)[i];
    ushort4 h;
    h.x = f2h(v.x); h.y = f2h(v.y); h.z = f2h(v.z); h.w = f2h(v.w);
    ((ushort4*)out)[i] = h;
}

__global__ __launch_bounds__(256) void transpose_f16(
    const float* __restrict__ W, u16* __restrict__ T, int K, int N, int rowoff)
{
    __shared__ float tile[32][33];
    const int k0 = blockIdx.x * 32;
    const int n0 = blockIdx.y * 32;
    const int tid = threadIdx.x;
#pragma unroll
    for (int i = 0; i < 4; ++i) {
        const int idx = tid + i * 256;
        const int r = idx >> 5, c = idx & 31;
        tile[r][c] = W[(size_t)(k0 + r) * N + n0 + c];
    }
    __syncthreads();
#pragma unroll
    for (int i = 0; i < 4; ++i) {
        const int idx = tid + i * 256;
        const int r = idx >> 5, c = idx & 31;
        T[(size_t)(rowoff + n0 + r) * K + k0 + c] = f2h(tile[c][r]);
    }
}

__global__ __launch_bounds__(256) void concat_bias(
    const float* __restrict__ bq, const float* __restrict__ bk,
    const float* __restrict__ bv, float* __restrict__ bc)
{
    const int i = blockIdx.x * 256 + threadIdx.x;
    float v;
    if (i < DIM) v = bq[i];
    else if (i < DIM + HD) v = bk[i - DIM];
    else v = bv[i - DIM - HD];
    bc[i] = v;
}

// ---------------------------------------------------------------------------
// fp16 GEMM: 128x128 tile, BK=32, dbuf LDS + global_load_lds, source-chunk
// swizzle (verified conflict-free).  MODE 0: QKV epilogue; MODE 1: f32 out.
// ---------------------------------------------------------------------------
template <int MODE>
__global__ __launch_bounds__(256) void gemm_f16(
    const u16* __restrict__ A, const u16* __restrict__ B,
    const float* __restrict__ bias, float* __restrict__ Cf,
    u16* __restrict__ qdst, u16* __restrict__ kdst, u16* __restrict__ vtdst,
    float scale)
{
    constexpr int BK = 32;
    __shared__ u16 lds[2][2 * 128 * BK];

    const int tid = threadIdx.x;
    const int wid = tid >> 6;
    const int lane = tid & 63;
    const int lr = lane & 15;
    const int lhi = lane >> 4;
    const int wr = wid >> 1, wc = wid & 1;
    const int bm = blockIdx.y * 128;
    const int bn = blockIdx.x * 128;

    f32x4 acc[4][4];
#pragma unroll
    for (int i = 0; i < 4; ++i)
#pragma unroll
        for (int j = 0; j < 4; ++j) acc[i][j] = (f32x4){0.f, 0.f, 0.f, 0.f};

#define STAGE(buf_, k0_)                                                      \
    {                                                                         \
        _Pragma("unroll")                                                     \
        for (int rr = 0; rr < 2; ++rr) {                                      \
            const int slot = rr * 256 + tid;                                  \
            const int row = slot >> 2;                                        \
            const int gch = ((slot & 3) ^ ((row >> 1) & 3)) * 8;              \
            char* lbase = (char*)lds[buf_] + (size_t)(rr * 256 + wid * 64) * 16; \
            gll16(A + (size_t)(bm + row) * DIM + (k0_) + gch, lbase);         \
            gll16(B + (size_t)(bn + row) * DIM + (k0_) + gch, lbase + 8192);  \
        }                                                                     \
    }

    STAGE(0, 0);
    __syncthreads();

    int cur = 0;
    for (int k0 = 0; k0 < DIM; k0 += BK) {
        if (k0 + BK < DIM) STAGE(cur ^ 1, k0 + BK);

        f16x8 a[4], b[4];
#pragma unroll
        for (int i = 0; i < 4; ++i) {
            const int mrow = wr * 64 + i * 16 + lr;
            const int nrow = wc * 64 + i * 16 + lr;
            a[i] = *(const f16x8*)&lds[cur][mrow * BK + ((lhi ^ ((mrow >> 1) & 3)) * 8)];
            b[i] = *(const f16x8*)&lds[cur][4096 + nrow * BK + ((lhi ^ ((nrow >> 1) & 3)) * 8)];
        }
        __builtin_amdgcn_s_setprio(1);
#pragma unroll
        for (int i = 0; i < 4; ++i)
#pragma unroll
            for (int j = 0; j < 4; ++j)
                acc[i][j] = __builtin_amdgcn_mfma_f32_16x16x32_f16(a[i], b[j], acc[i][j], 0, 0, 0);
        __builtin_amdgcn_s_setprio(0);
        __syncthreads();
        cur ^= 1;
    }
#undef STAGE

    const float alpha = (MODE == 0 && bn < DIM) ? scale : 1.0f;
    float bj[4];
#pragma unroll
    for (int j = 0; j < 4; ++j) bj[j] = bias[bn + wc * 64 + j * 16 + lr];

#pragma unroll
    for (int i = 0; i < 4; ++i) {
#pragma unroll
        for (int j = 0; j < 4; ++j) {
#pragma unroll
            for (int r = 0; r < 4; ++r) {
                const int row = bm + wr * 64 + i * 16 + lhi * 4 + r;
                const int col = bn + wc * 64 + j * 16 + lr;
                const float val = (acc[i][j][r] + bj[j]) * alpha;
                if (MODE == 1) {
                    Cf[(size_t)row * DIM + col] = val;
                } else if (bn < DIM) {
                    qdst[(size_t)row * DIM + col] = f2h(val);
                } else if (bn < DIM + HD) {
                    kdst[(size_t)row * HD + (col - DIM)] = f2h(val);
                } else {
                    vtdst[(size_t)(col - DIM - HD) * TOKENS + row] = f2h(val);
                }
            }
        }
    }
}

// ---------------------------------------------------------------------------
// MQA flash attention, swapped-operand form (T12): sc^T = mfma(K, Q) puts
// all scores of q-row lr in the lane column; softmax in-register; P packed
// with cvt_pkrtz and redistributed to PV B-fragments via a 3-bit butterfly
// (shfl_xor(32)+select, then permlane16_swap).  O^T = mfma(V^T, P^T).
// K/V double-buffered LDS via global_load_lds w/ pre-swizzled source.
// ---------------------------------------------------------------------------
__global__ __launch_bounds__(256, 2) void mqa_attn_f16(
    const u16* __restrict__ Q, const u16* __restrict__ Kg,
    const u16* __restrict__ Vtg, u16* __restrict__ Oh)
{
    __shared__ __align__(16) u16 Ks[2][64 * 128];   // 32 KB
    __shared__ __align__(16) u16 Vt[2][128 * 64];   // 32 KB

    const int tid = threadIdx.x;
    const int wid = tid >> 6;
    const int lane = tid & 63;
    const int lr = lane & 15;
    const int lhi = lane >> 4;
    const bool l5 = (lhi & 2) != 0;   // lane bit 5

    const int qt = blockIdx.x;
    const int h  = blockIdx.y;
    const int b  = blockIdx.z;
    const size_t bseq = (size_t)b * SEQ;
    const int q0 = qt * 128 + wid * 32;

    // Q fragments (same storage serves as B-operand of swapped QK^T)
    f16x8 qf[2][4];
#pragma unroll
    for (int mt = 0; mt < 2; ++mt) {
        const u16* qrow = Q + (bseq + q0 + mt * 16 + lr) * DIM + (size_t)h * HD;
#pragma unroll
        for (int kk = 0; kk < 4; ++kk)
            qf[mt][kk] = *(const f16x8*)(qrow + kk * 32 + lhi * 8);
    }

    f16x8 ones;
#pragma unroll
    for (int j = 0; j < 8; ++j) ones[j] = (_Float16)1.0f;

    f32x4 o[2][8];
#pragma unroll
    for (int mt = 0; mt < 2; ++mt)
#pragma unroll
        for (int dt = 0; dt < 8; ++dt) o[mt][dt] = (f32x4){0.f, 0.f, 0.f, 0.f};
    float m[2]    = {-INFINITY, -INFINITY};
    float lsum[2] = {0.f, 0.f};

#define STAGE_KV(buf_, t0_)                                                   \
    {                                                                         \
        _Pragma("unroll")                                                     \
        for (int i = 0; i < 4; ++i) {                                         \
            const int L = i * 256 + tid;                                      \
            char* kbase = (char*)&Ks[buf_][0] + (size_t)(i * 256 + wid * 64) * 16; \
            char* vbase = (char*)&Vt[buf_][0] + (size_t)(i * 256 + wid * 64) * 16; \
            const int krow = L >> 4, kc = (L & 15) ^ ((L >> 4) & 7);          \
            const int vrow = L >> 3, vc = (L & 7) ^ ((L >> 3) & 7);           \
            gll16(&Kg[(bseq + (t0_) + krow) * HD + kc * 8], kbase);           \
            gll16(&Vtg[(size_t)vrow * TOKENS + bseq + (t0_) + vc * 8], vbase);\
        }                                                                     \
    }

    STAGE_KV(0, 0);
    __syncthreads();

    int cur = 0;
    for (int t0 = 0; t0 < SEQ; t0 += 64) {
        if (t0 + 64 < SEQ) STAGE_KV(cur ^ 1, t0 + 64);

        // ---- QK^T (swapped): sc[mt][ct] = S^T[kv=ct*16+lhi*4+r][q=mt*16+lr]
        f32x4 sc[2][4];
#pragma unroll
        for (int mt = 0; mt < 2; ++mt)
#pragma unroll
            for (int ct = 0; ct < 4; ++ct) sc[mt][ct] = (f32x4){0.f, 0.f, 0.f, 0.f};
        __builtin_amdgcn_s_setprio(1);
#pragma unroll
        for (int kk = 0; kk < 4; ++kk)
#pragma unroll
            for (int ct = 0; ct < 4; ++ct) {
                const f16x8 kf = *(const f16x8*)&Ks[cur][KIDX(ct * 16 + lr, kk * 32 + lhi * 8)];
                sc[0][ct] = __builtin_amdgcn_mfma_f32_16x16x32_f16(kf, qf[0][kk], sc[0][ct], 0, 0, 0);
                sc[1][ct] = __builtin_amdgcn_mfma_f32_16x16x32_f16(kf, qf[1][kk], sc[1][ct], 0, 0, 0);
            }
        __builtin_amdgcn_s_setprio(0);

        // ---- softmax + P pack/redistribute, per m-tile ----
        frag_u pa[2][2];
        float al[2];
#pragma unroll
        for (int mt = 0; mt < 2; ++mt) {
            // row max: 16 in-lane + 2 cross-lane
            float pm = fmaxf(fmaxf(fmaxf(sc[mt][0][0], sc[mt][0][1]),
                                   fmaxf(sc[mt][0][2], sc[mt][0][3])),
                             fmaxf(fmaxf(sc[mt][1][0], sc[mt][1][1]),
                                   fmaxf(sc[mt][1][2], sc[mt][1][3])));
            pm = fmaxf(pm, fmaxf(fmaxf(fmaxf(sc[mt][2][0], sc[mt][2][1]),
                                       fmaxf(sc[mt][2][2], sc[mt][2][3])),
                                 fmaxf(fmaxf(sc[mt][3][0], sc[mt][3][1]),
                                       fmaxf(sc[mt][3][2], sc[mt][3][3]))));
            pm = fmaxf(pm, __shfl_xor(pm, 16));
            pm = fmaxf(pm, __shfl_xor(pm, 32));

            // defer-max (THR=8)
            const bool grow = pm > m[mt] + 8.f;
            al[mt] = 1.f;
            if (__any(grow)) {
                if (grow) { al[mt] = __expf(m[mt] - pm); m[mt] = pm; }
#pragma unroll
                for (int dt = 0; dt < 8; ++dt)
#pragma unroll
                    for (int r = 0; r < 4; ++r)
                        o[mt][dt][r] *= al[mt];
            }

            // P = exp(S - m), packed rtz to fp16 pairs
            u32 pk[4][2];
#pragma unroll
            for (int ct = 0; ct < 4; ++ct) {
                const float p0 = __expf(sc[mt][ct][0] - m[mt]);
                const float p1 = __expf(sc[mt][ct][1] - m[mt]);
                const float p2 = __expf(sc[mt][ct][2] - m[mt]);
                const float p3 = __expf(sc[mt][ct][3] - m[mt]);
                pk[ct][0] = __builtin_bit_cast(u32, __builtin_amdgcn_cvt_pkrtz(p0, p1));
                pk[ct][1] = __builtin_bit_cast(u32, __builtin_amdgcn_cvt_pkrtz(p2, p3));
            }

            // butterfly: swap(lane-b5, pair) via shfl+sel, swap(lane-b4, pair)
            // via permlane16_swap.  Result: pa[kk][j] = P[q=mt*16+lr][kk*32+lhi*8+j]
#pragma unroll
            for (int kk = 0; kk < 2; ++kk)
#pragma unroll
                for (int p = 0; p < 2; ++p) {
                    const u32 X = pk[2 * kk + 0][p];
                    const u32 Y = pk[2 * kk + 1][p];
                    const u32 sx = __shfl_xor(X, 32);
                    const u32 sy = __shfl_xor(Y, 32);
                    const u32 X1 = l5 ? sy : X;
                    const u32 Y1 = l5 ? Y : sx;
                    const auto u2 = __builtin_amdgcn_permlane16_swap(X1, Y1, false, false);
                    pa[mt][kk].d[p]     = u2[0];
                    pa[mt][kk].d[2 + p] = u2[1];
                }
        }

        // ---- PV (joint over m-tiles; vf shared) + row-sum via ones-MFMA ----
        f32x4 lacc[2];
        lacc[0] = (f32x4){0.f, 0.f, 0.f, 0.f};
        lacc[1] = (f32x4){0.f, 0.f, 0.f, 0.f};
        __builtin_amdgcn_s_setprio(1);
#pragma unroll
        for (int kk = 0; kk < 2; ++kk) {
            lacc[0] = __builtin_amdgcn_mfma_f32_16x16x32_f16(ones, pa[0][kk].v, lacc[0], 0, 0, 0);
            lacc[1] = __builtin_amdgcn_mfma_f32_16x16x32_f16(ones, pa[1][kk].v, lacc[1], 0, 0, 0);
#pragma unroll
            for (int dt = 0; dt < 8; ++dt) {
                const f16x8 vf = *(const f16x8*)&Vt[cur][VIDX(dt * 16 + lr, kk * 32 + lhi * 8)];
                o[0][dt] = __builtin_amdgcn_mfma_f32_16x16x32_f16(vf, pa[0][kk].v, o[0][dt], 0, 0, 0);
                o[1][dt] = __builtin_amdgcn_mfma_f32_16x16x32_f16(vf, pa[1][kk].v, o[1][dt], 0, 0, 0);
            }
        }
        __builtin_amdgcn_s_setprio(0);
#pragma unroll
        for (int mt = 0; mt < 2; ++mt)
            lsum[mt] = lsum[mt] * al[mt] + lacc[mt][0];

        __syncthreads();   // drains prefetch vmcnt; releases read buffer
        cur ^= 1;
    }
#undef STAGE_KV

    // ---- epilogue: O^T regs -> O[token][feature], 8B packed stores ----
#pragma unroll
    for (int mt = 0; mt < 2; ++mt) {
        const float inv = 1.f / lsum[mt];
        const size_t base = (bseq + q0 + mt * 16 + lr) * DIM + (size_t)h * HD + lhi * 4;
#pragma unroll
        for (int dt = 0; dt < 8; ++dt) {
            ushort4 h4;
            h4.x = f2h(o[mt][dt][0] * inv);
            h4.y = f2h(o[mt][dt][1] * inv);
            h4.z = f2h(o[mt][dt][2] * inv);
            h4.w = f2h(o[mt][dt][3] * inv);
            *(ushort4*)&Oh[base + dt * 16] = h4;
        }
    }
}

// ---------------------------------------------------------------------------
extern "C" void kernel_launch(void* const* d_in, const int* in_sizes, int n_in,
                              void* d_out, int out_size, void* d_ws, size_t ws_size,
                              hipStream_t stream) {
    const float* x  = (const float*)d_in[0];
    const float* wq = (const float*)d_in[1];
    const float* bq = (const float*)d_in[2];
    const float* wk = (const float*)d_in[3];
    const float* bk = (const float*)d_in[4];
    const float* wv = (const float*)d_in[5];
    const float* bv = (const float*)d_in[6];
    const float* wo = (const float*)d_in[7];
    const float* bo = (const float*)d_in[8];
    float* out = (float*)d_out;

    char* w = (char*)d_ws;
    u16* xh     = (u16*)w;                 w += (size_t)TOKENS * DIM * 2;
    u16* wcat   = (u16*)w;                 w += (size_t)NQKV * DIM * 2;
    u16* woT    = (u16*)w;                 w += (size_t)DIM * DIM * 2;
    u16* qb     = (u16*)w;                 w += (size_t)TOKENS * DIM * 2;
    u16* kb     = (u16*)w;                 w += (size_t)TOKENS * HD * 2;
    u16* vtb    = (u16*)w;                 w += (size_t)TOKENS * HD * 2;
    float* bc   = (float*)w;               w += 16384;
    u16* Oh = xh;   // x dead after QKV GEMM; stream order makes this safe

    const float scale = 0.08838834764831845f;  // 1/sqrt(128)
    const dim3 blk(256);

    conv_f16<<<TOKENS * DIM / 4 / 256, blk, 0, stream>>>(x, xh);
    transpose_f16<<<dim3(DIM / 32, DIM / 32), blk, 0, stream>>>(wq, wcat, DIM, DIM, 0);
    transpose_f16<<<dim3(DIM / 32, HD / 32), blk, 0, stream>>>(wk, wcat, DIM, HD, DIM);
    transpose_f16<<<dim3(DIM / 32, HD / 32), blk, 0, stream>>>(wv, wcat, DIM, HD, DIM + HD);
    transpose_f16<<<dim3(DIM / 32, DIM / 32), blk, 0, stream>>>(wo, woT, DIM, DIM, 0);
    concat_bias<<<NQKV / 256, blk, 0, stream>>>(bq, bk, bv, bc);

    gemm_f16<0><<<dim3(NQKV / 128, TOKENS / 128), blk, 0, stream>>>(
        xh, wcat, bc, nullptr, qb, kb, vtb, scale);

    mqa_attn_f16<<<dim3(SEQ / 128, NH, BATCH), blk, 0, stream>>>(qb, kb, vtb, Oh);

    gemm_f16<1><<<dim3(DIM / 128, TOKENS / 128), blk, 0, stream>>>(
        Oh, woT, bo, out, nullptr, nullptr, nullptr, 1.0f);
}